// Round 19
// baseline (174.345 us; speedup 1.0000x reference)
//
#include <hip/hip_runtime.h>
#include <hip/hip_bf16.h>
#include <math.h>

// Problem constants
constexpr int BB   = 2;
constexpr int SS   = 1024;
constexpr int HID  = 2048;
constexpr int NH   = 32;
constexpr int NKV  = 8;
constexpr int HD   = 64;
constexpr int M    = BB * SS;          // 2048 rows
constexpr int NQKV = 3072;             // fused q|k|v output width

typedef __attribute__((ext_vector_type(8))) short bf8v;   // 8 bf16
typedef __attribute__((ext_vector_type(4))) float f4v;    // 4 f32 acc

static __device__ __forceinline__ unsigned short f2b(float x) {
  __hip_bfloat16 h = __float2bfloat16(x);
  return *reinterpret_cast<unsigned short*>(&h);
}
static __device__ __forceinline__ void gload16(void* lds, const void* g) {
  __builtin_amdgcn_global_load_lds(
      (const __attribute__((address_space(1))) void*)g,
      (__attribute__((address_space(3))) void*)lds, 16, 0, 0);
}

// ---------------------------------------------------------------------------
// Fused prep (one launch, grid 32x32x6): weight transposes, RoPE table, castX
// ---------------------------------------------------------------------------
__global__ __launch_bounds__(256) void prepAll(
    const float* __restrict__ Wq, const float* __restrict__ Wk,
    const float* __restrict__ Wv, const float* __restrict__ Wo,
    const float* __restrict__ hidden, const int* __restrict__ pos_ids,
    unsigned short* __restrict__ WqkvT, unsigned short* __restrict__ WoT,
    unsigned short* __restrict__ Xb, float2* __restrict__ tab) {
  const int z = blockIdx.z;
  const int t = threadIdx.x;

  if (z == 4) {            // RoPE table
    const int idx = blockIdx.y * 32 + blockIdx.x;
    if ((t & 127) < 32) {
      const int m = idx * 2 + (t >> 7);
      const int j = t & 31;
      const float pos = (float)pos_ids[m];
      const float ang = pos * exp2f(-(float)j * (13.287712379549449f / 32.0f));
      float sn, cs;
      sincosf(ang, &sn, &cs);
      tab[(size_t)m * 32 + j] = make_float2(cs, sn);
    }
    return;
  }
  if (z == 5) {            // castX
    const size_t base = ((size_t)(blockIdx.y * 32 + blockIdx.x)) * 4096;
#pragma unroll
    for (int it = 0; it < 2; ++it) {
      const size_t i = base + it * 2048 + t * 8;
      const float4 v0 = *(const float4*)(hidden + i);
      const float4 v1 = *(const float4*)(hidden + i + 4);
      unsigned short o[8] = {f2b(v0.x), f2b(v0.y), f2b(v0.z), f2b(v0.w),
                             f2b(v1.x), f2b(v1.y), f2b(v1.z), f2b(v1.w)};
      *(bf8v*)(Xb + i) = *(bf8v*)o;
    }
    return;
  }

  const float* src;
  unsigned short* dst;
  int C;
  if (z == 0)      { src = Wq; dst = WqkvT;                      C = 2048; }
  else if (z == 1) { src = Wk; dst = WqkvT + (size_t)2048 * HID; C = 512;  }
  else if (z == 2) { src = Wv; dst = WqkvT + (size_t)2560 * HID; C = 512;  }
  else             { src = Wo; dst = WoT;                        C = 2048; }

  const int r0 = blockIdx.y * 64, c0 = blockIdx.x * 64;
  if (c0 >= C) return;
  __shared__ float T[64][65];
  {
    const int r  = t >> 2;
    const int c4 = (t & 3) * 16;
    const float* sp = src + (size_t)(r0 + r) * C + c0 + c4;
    *(float4*)&T[r][c4 + 0]  = *(const float4*)(sp + 0);
    *(float4*)&T[r][c4 + 4]  = *(const float4*)(sp + 4);
    *(float4*)&T[r][c4 + 8]  = *(const float4*)(sp + 8);
    *(float4*)&T[r][c4 + 12] = *(const float4*)(sp + 12);
  }
  __syncthreads();
  {
    const int c  = t >> 2;
    const int rr = (t & 3) * 16;
    unsigned short o[16];
#pragma unroll
    for (int i = 0; i < 16; ++i) o[i] = f2b(T[rr + i][c]);
    unsigned short* dp = dst + (size_t)(c0 + c) * HID + r0 + rr;
    *(bf8v*)dp       = *(bf8v*)&o[0];
    *(bf8v*)(dp + 8) = *(bf8v*)&o[8];
  }
}

// ===========================================================================
// GEMM core: 128x128 tile (halves L2 traffic vs 64x128: A+B re-reads
// QKV 590->384 MB, Wo 384->256 MB — the round-18 analysis showed we sustain
// ~10.5 TB/s aggregate L2, i.e. traffic-bound once depth-3 hides latency).
// 4 waves 2x2 (each wave 64x64 = 4x4 MFMA), BK=32, 64 steps.
// T4 depth-3: 4 LDS buffers (64KB -> 2 blocks/CU), per-wave 4 loads/stage,
// wait vmcnt(8) => buffer t+1 landed, t+2/t+3 in flight. Tail 8/4/0.
// T2 both-sides 16B-slot swizzle (0 conflicts, r16-verified).
// XCD-ownership 1-D grid swizzle (bn-slices pinned per XCD).
// ===========================================================================

// ---------------------------------------------------------------------------
// QKV GEMM with fused RoPE epilogue. Grid: 384 1-D.
// ---------------------------------------------------------------------------
__global__ __launch_bounds__(256) void gemm_qkv(
    const unsigned short* __restrict__ A, const unsigned short* __restrict__ Bt,
    const float2* __restrict__ tab,
    unsigned short* __restrict__ Qb, unsigned short* __restrict__ Kb,
    unsigned short* __restrict__ Vb) {
  __shared__ unsigned short As[4][128 * 32];
  __shared__ unsigned short Bs[4][128 * 32];
  const int t  = threadIdx.x;
  const int w  = t >> 6, l = t & 63;
  const int lr = l & 15, lg = l >> 4;
  const int wr = w >> 1, wc = w & 1;
  // XCD swizzle: XCD g owns bn tiles [3g, 3g+3)  (24 bn tiles / 8 XCDs)
  const int L = blockIdx.x;
  const int g = L & 7, s5 = L >> 3;            // s5: 0..47
  const int bn = (g * 3 + (s5 % 3)) * 128;
  const int bm = (s5 / 3) * 128;

  f4v acc[4][4] = {};

  const unsigned short* Ablk = A  + (size_t)bm * HID;
  const unsigned short* Bblk = Bt + (size_t)bn * HID;
  const int srow = l >> 2;
  const int scol = (((l & 3) ^ ((srow >> 1) & 3)) * 8);
  const int rsl  = (lg ^ ((lr >> 1) & 3)) * 8;

  auto stage = [&](int buf, int k0) {
    gload16(&As[buf][(w * 32)      * 32], Ablk + (size_t)(w * 32 +      srow) * HID + k0 + scol);
    gload16(&As[buf][(w * 32 + 16) * 32], Ablk + (size_t)(w * 32 + 16 + srow) * HID + k0 + scol);
    gload16(&Bs[buf][(w * 32)      * 32], Bblk + (size_t)(w * 32 +      srow) * HID + k0 + scol);
    gload16(&Bs[buf][(w * 32 + 16) * 32], Bblk + (size_t)(w * 32 + 16 + srow) * HID + k0 + scol);
  };

  const int nsteps = HID / 32;           // 64
  stage(0, 0);
  stage(1, 32);
  stage(2, 64);
  asm volatile("s_waitcnt vmcnt(8)" ::: "memory");   // buf0 landed
  __builtin_amdgcn_s_barrier();

  const int aoff = (wr * 64 + lr) * 32 + rsl;
  const int boff = (wc * 64 + lr) * 32 + rsl;
  for (int tt = 0; tt < nsteps; ++tt) {
    const int cur = tt & 3;
    if (tt + 3 < nsteps) stage((tt + 3) & 3, (tt + 3) * 32);

    bf8v aF[4], bF[4];
#pragma unroll
    for (int i = 0; i < 4; ++i) {
      aF[i] = *(const bf8v*)&As[cur][aoff + i * 512];
      bF[i] = *(const bf8v*)&Bs[cur][boff + i * 512];
    }
    __builtin_amdgcn_s_setprio(1);
#pragma unroll
    for (int mi = 0; mi < 4; ++mi)
#pragma unroll
      for (int ni = 0; ni < 4; ++ni)
        acc[mi][ni] = __builtin_amdgcn_mfma_f32_16x16x32_bf16(aF[mi], bF[ni], acc[mi][ni], 0, 0, 0);
    __builtin_amdgcn_s_setprio(0);

    if (tt + 3 < nsteps)      { asm volatile("s_waitcnt vmcnt(8)" ::: "memory"); }
    else if (tt + 2 < nsteps) { asm volatile("s_waitcnt vmcnt(4)" ::: "memory"); }
    else                      { asm volatile("s_waitcnt vmcnt(0)" ::: "memory"); }
    __builtin_amdgcn_s_barrier();
  }

  // Fused RoPE epilogue. D layout: row = lg*4+r, col = lr (m89/m91).
  const int row0 = bm + wr * 64;
  const int colHead = bn + wc * 64;
  unsigned short* outArr;
  int hh, headsPerB, mode;                   // 0=Q(rope+scale) 1=K(rope) 2=V
  if (colHead < 2048)      { mode = 0; outArr = Qb; hh = colHead >> 6;          headsPerB = NH;  }
  else if (colHead < 2560) { mode = 1; outArr = Kb; hh = (colHead - 2048) >> 6; headsPerB = NKV; }
  else                     { mode = 2; outArr = Vb; hh = (colHead - 2560) >> 6; headsPerB = NKV; }

#pragma unroll
  for (int mi = 0; mi < 4; ++mi)
#pragma unroll
    for (int r = 0; r < 4; ++r) {
      const int rowg = row0 + mi * 16 + lg * 4 + r;
      const int bI = rowg >> 10, s = rowg & (SS - 1);
      unsigned short* dst =
          outArr + ((size_t)(bI * headsPerB + hh) * SS + s) * 64;
      if (mode == 2) {
#pragma unroll
        for (int ni = 0; ni < 4; ++ni)
          dst[ni * 16 + lr] = f2b(acc[mi][ni][r]);
      } else {
        const float2 cs_lo = tab[(size_t)rowg * 32 + lr];
        const float2 cs_hi = tab[(size_t)rowg * 32 + 16 + lr];
#pragma unroll
        for (int ni = 0; ni < 4; ++ni) {
          const float2 cs = (ni & 1) ? cs_hi : cs_lo;
          const float x   = acc[mi][ni][r];
          const float prt = acc[mi][ni ^ 2][r];
          const float rh  = (ni < 2) ? -prt : prt;
          float v = x * cs.x + rh * cs.y;
          if (mode == 0) v *= 0.125f;
          dst[ni * 16 + lr] = f2b(v);
        }
      }
    }
}

// ---------------------------------------------------------------------------
// Plain bf16 GEMM for Wo. Grid: 256 1-D (1 block/CU exact). f32 out.
// ---------------------------------------------------------------------------
__global__ __launch_bounds__(256) void gemm_bf16(
    const unsigned short* __restrict__ A, const unsigned short* __restrict__ Bt,
    float* __restrict__ C, int Ndim) {
  __shared__ unsigned short As[4][128 * 32];
  __shared__ unsigned short Bs[4][128 * 32];
  const int t  = threadIdx.x;
  const int w  = t >> 6, l = t & 63;
  const int lr = l & 15, lg = l >> 4;
  const int wr = w >> 1, wc = w & 1;
  // XCD swizzle: XCD g owns bn tiles [2g, 2g+2)  (16 bn tiles / 8 XCDs)
  const int L = blockIdx.x;
  const int g = L & 7, s5 = L >> 3;            // s5: 0..31
  const int bn = (g * 2 + (s5 & 1)) * 128;
  const int bm = (s5 >> 1) * 128;

  f4v acc[4][4] = {};

  const unsigned short* Ablk = A  + (size_t)bm * HID;
  const unsigned short* Bblk = Bt + (size_t)bn * HID;
  const int srow = l >> 2;
  const int scol = (((l & 3) ^ ((srow >> 1) & 3)) * 8);
  const int rsl  = (lg ^ ((lr >> 1) & 3)) * 8;

  auto stage = [&](int buf, int k0) {
    gload16(&As[buf][(w * 32)      * 32], Ablk + (size_t)(w * 32 +      srow) * HID + k0 + scol);
    gload16(&As[buf][(w * 32 + 16) * 32], Ablk + (size_t)(w * 32 + 16 + srow) * HID + k0 + scol);
    gload16(&Bs[buf][(w * 32)      * 32], Bblk + (size_t)(w * 32 +      srow) * HID + k0 + scol);
    gload16(&Bs[buf][(w * 32 + 16) * 32], Bblk + (size_t)(w * 32 + 16 + srow) * HID + k0 + scol);
  };

  const int nsteps = HID / 32;
  stage(0, 0);
  stage(1, 32);
  stage(2, 64);
  asm volatile("s_waitcnt vmcnt(8)" ::: "memory");
  __builtin_amdgcn_s_barrier();

  const int aoff = (wr * 64 + lr) * 32 + rsl;
  const int boff = (wc * 64 + lr) * 32 + rsl;
  for (int tt = 0; tt < nsteps; ++tt) {
    const int cur = tt & 3;
    if (tt + 3 < nsteps) stage((tt + 3) & 3, (tt + 3) * 32);

    bf8v aF[4], bF[4];
#pragma unroll
    for (int i = 0; i < 4; ++i) {
      aF[i] = *(const bf8v*)&As[cur][aoff + i * 512];
      bF[i] = *(const bf8v*)&Bs[cur][boff + i * 512];
    }
    __builtin_amdgcn_s_setprio(1);
#pragma unroll
    for (int mi = 0; mi < 4; ++mi)
#pragma unroll
      for (int ni = 0; ni < 4; ++ni)
        acc[mi][ni] = __builtin_amdgcn_mfma_f32_16x16x32_bf16(aF[mi], bF[ni], acc[mi][ni], 0, 0, 0);
    __builtin_amdgcn_s_setprio(0);

    if (tt + 3 < nsteps)      { asm volatile("s_waitcnt vmcnt(8)" ::: "memory"); }
    else if (tt + 2 < nsteps) { asm volatile("s_waitcnt vmcnt(4)" ::: "memory"); }
    else                      { asm volatile("s_waitcnt vmcnt(0)" ::: "memory"); }
    __builtin_amdgcn_s_barrier();
  }

  const int row0 = bm + wr * 64;
  const int col0 = bn + wc * 64;
#pragma unroll
  for (int mi = 0; mi < 4; ++mi)
#pragma unroll
    for (int r = 0; r < 4; ++r) {
      const size_t rowoff = (size_t)(row0 + mi * 16 + lg * 4 + r) * Ndim;
#pragma unroll
      for (int ni = 0; ni < 4; ++ni)
        C[rowoff + col0 + ni * 16 + lr] = acc[mi][ni][r];
    }
}

// ---------------------------------------------------------------------------
// V transpose: Vb [bkv][s][64] -> Vt [bkv][64][S]   (bf16)
// ---------------------------------------------------------------------------
__global__ __launch_bounds__(256) void vtrans(
    const unsigned short* __restrict__ Vb, unsigned short* __restrict__ Vt) {
  const int bkv = blockIdx.y;
  const int s0  = blockIdx.x * 64;
  __shared__ unsigned short T[64][72];
  const int t = threadIdx.x;
  const unsigned short* src = Vb + ((size_t)bkv * SS + s0) * 64;
  {
    const int r  = t >> 2;
    const int co = (t & 3) * 16;
    *(bf8v*)&T[r][co]     = *(const bf8v*)(src + (size_t)r * 64 + co);
    *(bf8v*)&T[r][co + 8] = *(const bf8v*)(src + (size_t)r * 64 + co + 8);
  }
  __syncthreads();
  {
    const int d  = t >> 2;
    const int so = (t & 3) * 16;
    unsigned short tmp[16];
#pragma unroll
    for (int i = 0; i < 16; ++i) tmp[i] = T[so + i][d];
    unsigned short* dst = Vt + ((size_t)(bkv * 64 + d)) * SS + s0 + so;
    *(bf8v*)dst       = *(bf8v*)&tmp[0];
    *(bf8v*)(dst + 8) = *(bf8v*)&tmp[8];
  }
}

// ---------------------------------------------------------------------------
// Flash attention (round-11 two-barrier structure, measured best 52.9us).
// ---------------------------------------------------------------------------
__global__ __launch_bounds__(128) void attn_mfma(
    const unsigned short* __restrict__ Qb, const unsigned short* __restrict__ Kb,
    const unsigned short* __restrict__ Vt, unsigned short* __restrict__ attn) {
  const int xb = blockIdx.x;
  const int h = blockIdx.y, b = blockIdx.z;
  const int kv = h >> 2;
  const int w  = threadIdx.x >> 6;
  const int l  = threadIdx.x & 63;
  const int lr = l & 15;
  const int lg = l >> 4;
  const int t  = threadIdx.x;

  __shared__ unsigned short VT[64][72];
  __shared__ unsigned short PL[2][16][72];

  const unsigned short* Kp = Kb + ((size_t)((b * NKV + kv) * SS)) * 64;
  const unsigned short* Vp = Vt + ((size_t)((b * NKV + kv) * 64)) * SS;

  const int vd  = t >> 1;
  const int vso = (t & 1) * 32;

  for (int half = 0; half < 2; ++half) {
    const int qt = half ? (31 - xb) : xb;
    const int qbase = qt * 32;
    const int qW = qbase + w * 16;
    const unsigned short* Qp = Qb + ((size_t)((b * NH + h) * SS + qW)) * 64;
    bf8v aQ0 = *(const bf8v*)(Qp + (size_t)lr * 64 + lg * 8);
    bf8v aQ1 = *(const bf8v*)(Qp + (size_t)lr * 64 + 32 + lg * 8);

    f4v o[4] = {{0,0,0,0},{0,0,0,0},{0,0,0,0},{0,0,0,0}};
    float lsumL[4] = {0.f, 0.f, 0.f, 0.f};

    for (int kvb = 0; kvb < qbase + 32; kvb += 64) {
      __syncthreads();
      const unsigned short* vp = Vp + (size_t)vd * SS + kvb + vso;
      const bf8v v0 = *(const bf8v*)(vp);
      const bf8v v1 = *(const bf8v*)(vp + 8);
      const bf8v v2 = *(const bf8v*)(vp + 16);
      const bf8v v3 = *(const bf8v*)(vp + 24);

      f4v sc[4] = {{0,0,0,0},{0,0,0,0},{0,0,0,0},{0,0,0,0}};
      __builtin_amdgcn_s_setprio(1);
#pragma unroll
      for (int c = 0; c < 4; ++c) {
        const unsigned short* kr = Kp + (size_t)(kvb + c * 16 + lr) * 64 + lg * 8;
        bf8v b0 = *(const bf8v*)(kr);
        bf8v b1 = *(const bf8v*)(kr + 32);
        sc[c] = __builtin_amdgcn_mfma_f32_16x16x32_bf16(aQ0, b0, sc[c], 0, 0, 0);
        sc[c] = __builtin_amdgcn_mfma_f32_16x16x32_bf16(aQ1, b1, sc[c], 0, 0, 0);
      }
      __builtin_amdgcn_s_setprio(0);

#pragma unroll
      for (int r = 0; r < 4; ++r) {
        const int qrow = qW + lg * 4 + r;
        float ps = 0.f;
        unsigned short pb[4];
#pragma unroll
        for (int c = 0; c < 4; ++c) {
          const float s = ((kvb + c * 16 + lr) > qrow) ? -INFINITY : sc[c][r];
          const float p = __expf(s);
          ps += p;
          pb[c] = f2b(p);
        }
        lsumL[r] += ps;
#pragma unroll
        for (int c = 0; c < 4; ++c) PL[w][lg * 4 + r][c * 16 + lr] = pb[c];
      }

      *(bf8v*)&VT[vd][vso]      = v0;
      *(bf8v*)&VT[vd][vso + 8]  = v1;
      *(bf8v*)&VT[vd][vso + 16] = v2;
      *(bf8v*)&VT[vd][vso + 24] = v3;

      __syncthreads();

      bf8v aP0 = *(const bf8v*)&PL[w][lr][lg * 8];
      bf8v aP1 = *(const bf8v*)&PL[w][lr][32 + lg * 8];
      __builtin_amdgcn_s_setprio(1);
#pragma unroll
      for (int n = 0; n < 4; ++n) {
        bf8v bV0 = *(const bf8v*)&VT[n * 16 + lr][lg * 8];
        bf8v bV1 = *(const bf8v*)&VT[n * 16 + lr][32 + lg * 8];
        o[n] = __builtin_amdgcn_mfma_f32_16x16x32_bf16(aP0, bV0, o[n], 0, 0, 0);
        o[n] = __builtin_amdgcn_mfma_f32_16x16x32_bf16(aP1, bV1, o[n], 0, 0, 0);
      }
      __builtin_amdgcn_s_setprio(0);
    }

#pragma unroll
    for (int r = 0; r < 4; ++r) {
      float ls = lsumL[r];
      ls += __shfl_xor(ls, 1);
      ls += __shfl_xor(ls, 2);
      ls += __shfl_xor(ls, 4);
      ls += __shfl_xor(ls, 8);
      const float inv = 1.0f / ls;
      const int row = qW + lg * 4 + r;
      unsigned short* dst = attn + (size_t)(b * SS + row) * HID + h * 64;
#pragma unroll
      for (int n = 0; n < 4; ++n) dst[n * 16 + lr] = f2b(o[n][r] * inv);
    }
  }
}

// ---------------------------------------------------------------------------
extern "C" void kernel_launch(void* const* d_in, const int* in_sizes, int n_in,
                              void* d_out, int out_size, void* d_ws, size_t ws_size,
                              hipStream_t stream) {
  const float* hidden = (const float*)d_in[0];
  const int*   pos    = (const int*)d_in[1];
  const float* Wq = (const float*)d_in[3];
  const float* Wk = (const float*)d_in[4];
  const float* Wv = (const float*)d_in[5];
  const float* Wo = (const float*)d_in[6];
  float* out = (float*)d_out;

  char* ws = (char*)d_ws;
  unsigned short* WqkvT = (unsigned short*)(ws);              // 12 MB  [3072][2048]
  unsigned short* WoT   = (unsigned short*)(ws + 12582912);   //  8 MB  [2048][2048]
  unsigned short* Xb    = (unsigned short*)(ws + 20971520);   //  8 MB  [M][2048]
  unsigned short* attnb = Xb;                                 // alias (Xb dead after gemm_qkv)
  unsigned short* Qb    = (unsigned short*)(ws + 29360128);   //  8 MB  [B][NH][S][64]
  unsigned short* Kb    = (unsigned short*)(ws + 37748736);   //  2 MB  [B][NKV][S][64]
  unsigned short* Vb    = (unsigned short*)(ws + 39845888);   //  2 MB  [B][NKV][S][64]
  unsigned short* Vt    = (unsigned short*)(ws + 41943040);   //  2 MB  [B*NKV][64][S]
  float2*         tab   = (float2*)(ws + 44040192);           // 512 KB [M][32]

  dim3 blk(256);

  prepAll<<<dim3(32, 32, 6), blk, 0, stream>>>(Wq, Wk, Wv, Wo, hidden, pos,
                                               WqkvT, WoT, Xb, tab);

  // QKV: 384 blocks 1-D, XCD-ownership swizzled, 128x128 tiles
  gemm_qkv<<<dim3(384), blk, 0, stream>>>(Xb, WqkvT, tab, Qb, Kb, Vb);

  vtrans<<<dim3(SS / 64, BB * NKV), blk, 0, stream>>>(Vb, Vt);

  attn_mfma<<<dim3(16, NH, BB), dim3(128), 0, stream>>>(Qb, Kb, Vt, attnb);

  // Wo: 256 blocks 1-D, XCD-ownership swizzled, 128x128 tiles
  gemm_bf16<<<dim3(256), blk, 0, stream>>>(attnb, WoT, out, HID);
}

// Round 20
// 154.460 us; speedup vs baseline: 1.1287x; 1.1287x over previous
//
#include <hip/hip_runtime.h>
#include <hip/hip_bf16.h>
#include <math.h>

// Problem constants
constexpr int BB   = 2;
constexpr int SS   = 1024;
constexpr int HID  = 2048;
constexpr int NH   = 32;
constexpr int NKV  = 8;
constexpr int HD   = 64;
constexpr int M    = BB * SS;          // 2048 rows
constexpr int NQKV = 3072;             // fused q|k|v output width

typedef __attribute__((ext_vector_type(8))) short bf8v;   // 8 bf16
typedef __attribute__((ext_vector_type(4))) float f4v;    // 4 f32 acc

static __device__ __forceinline__ unsigned short f2b(float x) {
  __hip_bfloat16 h = __float2bfloat16(x);
  return *reinterpret_cast<unsigned short*>(&h);
}
static __device__ __forceinline__ void gload16(void* lds, const void* g) {
  __builtin_amdgcn_global_load_lds(
      (const __attribute__((address_space(1))) void*)g,
      (__attribute__((address_space(3))) void*)lds, 16, 0, 0);
}

// ---------------------------------------------------------------------------
// Fused prep (one launch, grid 32x32x6): weight transposes, RoPE table, castX
// ---------------------------------------------------------------------------
__global__ __launch_bounds__(256) void prepAll(
    const float* __restrict__ Wq, const float* __restrict__ Wk,
    const float* __restrict__ Wv, const float* __restrict__ Wo,
    const float* __restrict__ hidden, const int* __restrict__ pos_ids,
    unsigned short* __restrict__ WqkvT, unsigned short* __restrict__ WoT,
    unsigned short* __restrict__ Xb, float2* __restrict__ tab) {
  const int z = blockIdx.z;
  const int t = threadIdx.x;

  if (z == 4) {            // RoPE table
    const int idx = blockIdx.y * 32 + blockIdx.x;
    if ((t & 127) < 32) {
      const int m = idx * 2 + (t >> 7);
      const int j = t & 31;
      const float pos = (float)pos_ids[m];
      const float ang = pos * exp2f(-(float)j * (13.287712379549449f / 32.0f));
      float sn, cs;
      sincosf(ang, &sn, &cs);
      tab[(size_t)m * 32 + j] = make_float2(cs, sn);
    }
    return;
  }
  if (z == 5) {            // castX
    const size_t base = ((size_t)(blockIdx.y * 32 + blockIdx.x)) * 4096;
#pragma unroll
    for (int it = 0; it < 2; ++it) {
      const size_t i = base + it * 2048 + t * 8;
      const float4 v0 = *(const float4*)(hidden + i);
      const float4 v1 = *(const float4*)(hidden + i + 4);
      unsigned short o[8] = {f2b(v0.x), f2b(v0.y), f2b(v0.z), f2b(v0.w),
                             f2b(v1.x), f2b(v1.y), f2b(v1.z), f2b(v1.w)};
      *(bf8v*)(Xb + i) = *(bf8v*)o;
    }
    return;
  }

  const float* src;
  unsigned short* dst;
  int C;
  if (z == 0)      { src = Wq; dst = WqkvT;                      C = 2048; }
  else if (z == 1) { src = Wk; dst = WqkvT + (size_t)2048 * HID; C = 512;  }
  else if (z == 2) { src = Wv; dst = WqkvT + (size_t)2560 * HID; C = 512;  }
  else             { src = Wo; dst = WoT;                        C = 2048; }

  const int r0 = blockIdx.y * 64, c0 = blockIdx.x * 64;
  if (c0 >= C) return;
  __shared__ float T[64][65];
  {
    const int r  = t >> 2;
    const int c4 = (t & 3) * 16;
    const float* sp = src + (size_t)(r0 + r) * C + c0 + c4;
    *(float4*)&T[r][c4 + 0]  = *(const float4*)(sp + 0);
    *(float4*)&T[r][c4 + 4]  = *(const float4*)(sp + 4);
    *(float4*)&T[r][c4 + 8]  = *(const float4*)(sp + 8);
    *(float4*)&T[r][c4 + 12] = *(const float4*)(sp + 12);
  }
  __syncthreads();
  {
    const int c  = t >> 2;
    const int rr = (t & 3) * 16;
    unsigned short o[16];
#pragma unroll
    for (int i = 0; i < 16; ++i) o[i] = f2b(T[rr + i][c]);
    unsigned short* dp = dst + (size_t)(c0 + c) * HID + r0 + rr;
    *(bf8v*)dp       = *(bf8v*)&o[0];
    *(bf8v*)(dp + 8) = *(bf8v*)&o[8];
  }
}

// ===========================================================================
// GEMM core (round-17 measured best): 64x128 tile, 4 waves 2x2 (each wave
// 32x64), BK=32, K=2048 (64 steps). Grids: QKV 768 = 3 blocks/CU exact,
// Wo 512 = 2/CU exact — this occupancy is what covers load latency; the
// kernel then runs at ~51 B/cyc/CU ≈ 90% of the per-CU L2 ceiling
// (traffic-bound; bigger tiles can't fill the grid, measured r19).
// T4 depth-3: 4 LDS buffers (48KB), vmcnt 6/3/0 across raw barriers.
// T2 both-sides 16B-slot swizzle (0 bank conflicts, r16-verified).
// ===========================================================================

// ---------------------------------------------------------------------------
// QKV GEMM with fused RoPE epilogue + fused V transpose (writes Vt directly).
// ---------------------------------------------------------------------------
__global__ __launch_bounds__(256) void gemm_qkv(
    const unsigned short* __restrict__ A, const unsigned short* __restrict__ Bt,
    const float2* __restrict__ tab,
    unsigned short* __restrict__ Qb, unsigned short* __restrict__ Kb,
    unsigned short* __restrict__ Vt) {
  __shared__ unsigned short As[4][64 * 32];
  __shared__ unsigned short Bs[4][128 * 32];
  const int t  = threadIdx.x;
  const int w  = t >> 6, l = t & 63;
  const int lr = l & 15, lg = l >> 4;
  const int wr = w >> 1, wc = w & 1;
  const int bm = blockIdx.y * 64, bn = blockIdx.x * 128;

  f4v acc[2][4] = {};

  const unsigned short* Ablk = A  + (size_t)bm * HID;
  const unsigned short* Bblk = Bt + (size_t)bn * HID;
  const int srow = l >> 2;
  const int scol = (((l & 3) ^ ((srow >> 1) & 3)) * 8);
  const int rsl  = (lg ^ ((lr >> 1) & 3)) * 8;

  auto stage = [&](int buf, int k0) {
    gload16(&As[buf][(w * 16) * 32], Ablk + (size_t)(w * 16 + srow) * HID + k0 + scol);
    gload16(&Bs[buf][(w * 32)      * 32], Bblk + (size_t)(w * 32 +      srow) * HID + k0 + scol);
    gload16(&Bs[buf][(w * 32 + 16) * 32], Bblk + (size_t)(w * 32 + 16 + srow) * HID + k0 + scol);
  };

  const int nsteps = HID / 32;           // 64
  stage(0, 0);
  stage(1, 32);
  stage(2, 64);
  asm volatile("s_waitcnt vmcnt(6)" ::: "memory");   // buf0 landed
  __builtin_amdgcn_s_barrier();

  const int aoff = (wr * 32 + lr) * 32 + rsl;
  const int boff = (wc * 64 + lr) * 32 + rsl;
  for (int tt = 0; tt < nsteps; ++tt) {
    const int cur = tt & 3;
    if (tt + 3 < nsteps) stage((tt + 3) & 3, (tt + 3) * 32);

    bf8v aF[2], bF[4];
#pragma unroll
    for (int i = 0; i < 2; ++i)
      aF[i] = *(const bf8v*)&As[cur][aoff + i * 512];
#pragma unroll
    for (int j = 0; j < 4; ++j)
      bF[j] = *(const bf8v*)&Bs[cur][boff + j * 512];
    __builtin_amdgcn_s_setprio(1);
#pragma unroll
    for (int mi = 0; mi < 2; ++mi)
#pragma unroll
      for (int ni = 0; ni < 4; ++ni)
        acc[mi][ni] = __builtin_amdgcn_mfma_f32_16x16x32_bf16(aF[mi], bF[ni], acc[mi][ni], 0, 0, 0);
    __builtin_amdgcn_s_setprio(0);

    if (tt + 3 < nsteps)      { asm volatile("s_waitcnt vmcnt(6)" ::: "memory"); }
    else if (tt + 2 < nsteps) { asm volatile("s_waitcnt vmcnt(3)" ::: "memory"); }
    else                      { asm volatile("s_waitcnt vmcnt(0)" ::: "memory"); }
    __builtin_amdgcn_s_barrier();
  }

  // Fused epilogue. D layout: row = lg*4+r, col = lr (m89/m91).
  const int row0 = bm + wr * 32;
  const int colHead = bn + wc * 64;
  int mode, hh;                               // 0=Q(rope+scale) 1=K(rope) 2=V(transposed)
  if (colHead < 2048)      { mode = 0; hh = colHead >> 6;          }
  else if (colHead < 2560) { mode = 1; hh = (colHead - 2048) >> 6; }
  else                     { mode = 2; hh = (colHead - 2560) >> 6; }

#pragma unroll
  for (int mi = 0; mi < 2; ++mi)
#pragma unroll
    for (int r = 0; r < 4; ++r) {
      const int rowg = row0 + mi * 16 + lg * 4 + r;
      const int bI = rowg >> 10, s = rowg & (SS - 1);
      if (mode == 2) {
        // V: write straight to Vt[(bI*NKV+hh)*64 + d][s]  (fused transpose)
        unsigned short* base = Vt + ((size_t)(bI * NKV + hh) * 64) * SS + s;
#pragma unroll
        for (int ni = 0; ni < 4; ++ni)
          base[(size_t)(ni * 16 + lr) * SS] = f2b(acc[mi][ni][r]);
      } else {
        unsigned short* dst = (mode == 0)
            ? Qb + ((size_t)(bI * NH  + hh) * SS + s) * 64
            : Kb + ((size_t)(bI * NKV + hh) * SS + s) * 64;
        const float2 cs_lo = tab[(size_t)rowg * 32 + lr];
        const float2 cs_hi = tab[(size_t)rowg * 32 + 16 + lr];
#pragma unroll
        for (int ni = 0; ni < 4; ++ni) {
          const float2 cs = (ni & 1) ? cs_hi : cs_lo;
          const float x   = acc[mi][ni][r];
          const float prt = acc[mi][ni ^ 2][r];
          const float rh  = (ni < 2) ? -prt : prt;
          float v = x * cs.x + rh * cs.y;
          if (mode == 0) v *= 0.125f;
          dst[ni * 16 + lr] = f2b(v);
        }
      }
    }
}

// ---------------------------------------------------------------------------
// Plain bf16 GEMM for Wo (same core), f32 out. Grid (16, 32) = 512 blocks.
// ---------------------------------------------------------------------------
__global__ __launch_bounds__(256) void gemm_bf16(
    const unsigned short* __restrict__ A, const unsigned short* __restrict__ Bt,
    float* __restrict__ C, int Ndim) {
  __shared__ unsigned short As[4][64 * 32];
  __shared__ unsigned short Bs[4][128 * 32];
  const int t  = threadIdx.x;
  const int w  = t >> 6, l = t & 63;
  const int lr = l & 15, lg = l >> 4;
  const int wr = w >> 1, wc = w & 1;
  const int bm = blockIdx.y * 64, bn = blockIdx.x * 128;

  f4v acc[2][4] = {};

  const unsigned short* Ablk = A  + (size_t)bm * HID;
  const unsigned short* Bblk = Bt + (size_t)bn * HID;
  const int srow = l >> 2;
  const int scol = (((l & 3) ^ ((srow >> 1) & 3)) * 8);
  const int rsl  = (lg ^ ((lr >> 1) & 3)) * 8;

  auto stage = [&](int buf, int k0) {
    gload16(&As[buf][(w * 16) * 32], Ablk + (size_t)(w * 16 + srow) * HID + k0 + scol);
    gload16(&Bs[buf][(w * 32)      * 32], Bblk + (size_t)(w * 32 +      srow) * HID + k0 + scol);
    gload16(&Bs[buf][(w * 32 + 16) * 32], Bblk + (size_t)(w * 32 + 16 + srow) * HID + k0 + scol);
  };

  const int nsteps = HID / 32;
  stage(0, 0);
  stage(1, 32);
  stage(2, 64);
  asm volatile("s_waitcnt vmcnt(6)" ::: "memory");
  __builtin_amdgcn_s_barrier();

  const int aoff = (wr * 32 + lr) * 32 + rsl;
  const int boff = (wc * 64 + lr) * 32 + rsl;
  for (int tt = 0; tt < nsteps; ++tt) {
    const int cur = tt & 3;
    if (tt + 3 < nsteps) stage((tt + 3) & 3, (tt + 3) * 32);

    bf8v aF[2], bF[4];
#pragma unroll
    for (int i = 0; i < 2; ++i)
      aF[i] = *(const bf8v*)&As[cur][aoff + i * 512];
#pragma unroll
    for (int j = 0; j < 4; ++j)
      bF[j] = *(const bf8v*)&Bs[cur][boff + j * 512];
    __builtin_amdgcn_s_setprio(1);
#pragma unroll
    for (int mi = 0; mi < 2; ++mi)
#pragma unroll
      for (int ni = 0; ni < 4; ++ni)
        acc[mi][ni] = __builtin_amdgcn_mfma_f32_16x16x32_bf16(aF[mi], bF[ni], acc[mi][ni], 0, 0, 0);
    __builtin_amdgcn_s_setprio(0);

    if (tt + 3 < nsteps)      { asm volatile("s_waitcnt vmcnt(6)" ::: "memory"); }
    else if (tt + 2 < nsteps) { asm volatile("s_waitcnt vmcnt(3)" ::: "memory"); }
    else                      { asm volatile("s_waitcnt vmcnt(0)" ::: "memory"); }
    __builtin_amdgcn_s_barrier();
  }

  const int row0 = bm + wr * 32;
  const int col0 = bn + wc * 64;
#pragma unroll
  for (int mi = 0; mi < 2; ++mi)
#pragma unroll
    for (int r = 0; r < 4; ++r) {
      const size_t rowoff = (size_t)(row0 + mi * 16 + lg * 4 + r) * Ndim;
#pragma unroll
      for (int ni = 0; ni < 4; ++ni)
        C[rowoff + col0 + ni * 16 + lr] = acc[mi][ni][r];
    }
}

// ---------------------------------------------------------------------------
// Flash attention (round-11 two-barrier structure, measured best 52.9us).
// ---------------------------------------------------------------------------
__global__ __launch_bounds__(128) void attn_mfma(
    const unsigned short* __restrict__ Qb, const unsigned short* __restrict__ Kb,
    const unsigned short* __restrict__ Vt, unsigned short* __restrict__ attn) {
  const int xb = blockIdx.x;
  const int h = blockIdx.y, b = blockIdx.z;
  const int kv = h >> 2;
  const int w  = threadIdx.x >> 6;
  const int l  = threadIdx.x & 63;
  const int lr = l & 15;
  const int lg = l >> 4;
  const int t  = threadIdx.x;

  __shared__ unsigned short VT[64][72];
  __shared__ unsigned short PL[2][16][72];

  const unsigned short* Kp = Kb + ((size_t)((b * NKV + kv) * SS)) * 64;
  const unsigned short* Vp = Vt + ((size_t)((b * NKV + kv) * 64)) * SS;

  const int vd  = t >> 1;
  const int vso = (t & 1) * 32;

  for (int half = 0; half < 2; ++half) {
    const int qt = half ? (31 - xb) : xb;
    const int qbase = qt * 32;
    const int qW = qbase + w * 16;
    const unsigned short* Qp = Qb + ((size_t)((b * NH + h) * SS + qW)) * 64;
    bf8v aQ0 = *(const bf8v*)(Qp + (size_t)lr * 64 + lg * 8);
    bf8v aQ1 = *(const bf8v*)(Qp + (size_t)lr * 64 + 32 + lg * 8);

    f4v o[4] = {{0,0,0,0},{0,0,0,0},{0,0,0,0},{0,0,0,0}};
    float lsumL[4] = {0.f, 0.f, 0.f, 0.f};

    for (int kvb = 0; kvb < qbase + 32; kvb += 64) {
      __syncthreads();
      const unsigned short* vp = Vp + (size_t)vd * SS + kvb + vso;
      const bf8v v0 = *(const bf8v*)(vp);
      const bf8v v1 = *(const bf8v*)(vp + 8);
      const bf8v v2 = *(const bf8v*)(vp + 16);
      const bf8v v3 = *(const bf8v*)(vp + 24);

      f4v sc[4] = {{0,0,0,0},{0,0,0,0},{0,0,0,0},{0,0,0,0}};
      __builtin_amdgcn_s_setprio(1);
#pragma unroll
      for (int c = 0; c < 4; ++c) {
        const unsigned short* kr = Kp + (size_t)(kvb + c * 16 + lr) * 64 + lg * 8;
        bf8v b0 = *(const bf8v*)(kr);
        bf8v b1 = *(const bf8v*)(kr + 32);
        sc[c] = __builtin_amdgcn_mfma_f32_16x16x32_bf16(aQ0, b0, sc[c], 0, 0, 0);
        sc[c] = __builtin_amdgcn_mfma_f32_16x16x32_bf16(aQ1, b1, sc[c], 0, 0, 0);
      }
      __builtin_amdgcn_s_setprio(0);

#pragma unroll
      for (int r = 0; r < 4; ++r) {
        const int qrow = qW + lg * 4 + r;
        float ps = 0.f;
        unsigned short pb[4];
#pragma unroll
        for (int c = 0; c < 4; ++c) {
          const float s = ((kvb + c * 16 + lr) > qrow) ? -INFINITY : sc[c][r];
          const float p = __expf(s);
          ps += p;
          pb[c] = f2b(p);
        }
        lsumL[r] += ps;
#pragma unroll
        for (int c = 0; c < 4; ++c) PL[w][lg * 4 + r][c * 16 + lr] = pb[c];
      }

      *(bf8v*)&VT[vd][vso]      = v0;
      *(bf8v*)&VT[vd][vso + 8]  = v1;
      *(bf8v*)&VT[vd][vso + 16] = v2;
      *(bf8v*)&VT[vd][vso + 24] = v3;

      __syncthreads();

      bf8v aP0 = *(const bf8v*)&PL[w][lr][lg * 8];
      bf8v aP1 = *(const bf8v*)&PL[w][lr][32 + lg * 8];
      __builtin_amdgcn_s_setprio(1);
#pragma unroll
      for (int n = 0; n < 4; ++n) {
        bf8v bV0 = *(const bf8v*)&VT[n * 16 + lr][lg * 8];
        bf8v bV1 = *(const bf8v*)&VT[n * 16 + lr][32 + lg * 8];
        o[n] = __builtin_amdgcn_mfma_f32_16x16x32_bf16(aP0, bV0, o[n], 0, 0, 0);
        o[n] = __builtin_amdgcn_mfma_f32_16x16x32_bf16(aP1, bV1, o[n], 0, 0, 0);
      }
      __builtin_amdgcn_s_setprio(0);
    }

#pragma unroll
    for (int r = 0; r < 4; ++r) {
      float ls = lsumL[r];
      ls += __shfl_xor(ls, 1);
      ls += __shfl_xor(ls, 2);
      ls += __shfl_xor(ls, 4);
      ls += __shfl_xor(ls, 8);
      const float inv = 1.0f / ls;
      const int row = qW + lg * 4 + r;
      unsigned short* dst = attn + (size_t)(b * SS + row) * HID + h * 64;
#pragma unroll
      for (int n = 0; n < 4; ++n) dst[n * 16 + lr] = f2b(o[n][r] * inv);
    }
  }
}

// ---------------------------------------------------------------------------
extern "C" void kernel_launch(void* const* d_in, const int* in_sizes, int n_in,
                              void* d_out, int out_size, void* d_ws, size_t ws_size,
                              hipStream_t stream) {
  const float* hidden = (const float*)d_in[0];
  const int*   pos    = (const int*)d_in[1];
  const float* Wq = (const float*)d_in[3];
  const float* Wk = (const float*)d_in[4];
  const float* Wv = (const float*)d_in[5];
  const float* Wo = (const float*)d_in[6];
  float* out = (float*)d_out;

  char* ws = (char*)d_ws;
  unsigned short* WqkvT = (unsigned short*)(ws);              // 12 MB  [3072][2048]
  unsigned short* WoT   = (unsigned short*)(ws + 12582912);   //  8 MB  [2048][2048]
  unsigned short* Xb    = (unsigned short*)(ws + 20971520);   //  8 MB  [M][2048]
  unsigned short* attnb = Xb;                                 // alias (Xb dead after gemm_qkv)
  unsigned short* Qb    = (unsigned short*)(ws + 29360128);   //  8 MB  [B][NH][S][64]
  unsigned short* Kb    = (unsigned short*)(ws + 37748736);   //  2 MB  [B][NKV][S][64]
  unsigned short* Vt    = (unsigned short*)(ws + 39845888);   //  2 MB  [B*NKV][64][S]
  float2*         tab   = (float2*)(ws + 41943040);           // 512 KB [M][32]

  dim3 blk(256);

  prepAll<<<dim3(32, 32, 6), blk, 0, stream>>>(Wq, Wk, Wv, Wo, hidden, pos,
                                               WqkvT, WoT, Xb, tab);

  // QKV: 24 x 32 = 768 blocks = 3 blocks/CU exact; V written transposed
  gemm_qkv<<<dim3(NQKV / 128, M / 64), blk, 0, stream>>>(Xb, WqkvT, tab, Qb, Kb, Vt);

  attn_mfma<<<dim3(16, NH, BB), dim3(128), 0, stream>>>(Qb, Kb, Vt, attnb);

  // Wo: 16 x 32 = 512 blocks = 2 blocks/CU exact
  gemm_bf16<<<dim3(HID / 128, M / 64), blk, 0, stream>>>(attnb, WoT, out, HID);
}

// Round 21
// 149.114 us; speedup vs baseline: 1.1692x; 1.0358x over previous
//
#include <hip/hip_runtime.h>
#include <hip/hip_bf16.h>
#include <math.h>

// Problem constants
constexpr int BB   = 2;
constexpr int SS   = 1024;
constexpr int HID  = 2048;
constexpr int NH   = 32;
constexpr int NKV  = 8;
constexpr int HD   = 64;
constexpr int M    = BB * SS;          // 2048 rows
constexpr int NQKV = 3072;             // fused q|k|v output width

typedef __attribute__((ext_vector_type(8))) short bf8v;   // 8 bf16
typedef __attribute__((ext_vector_type(4))) float f4v;    // 4 f32 acc

static __device__ __forceinline__ unsigned short f2b(float x) {
  __hip_bfloat16 h = __float2bfloat16(x);
  return *reinterpret_cast<unsigned short*>(&h);
}
static __device__ __forceinline__ void gload16(void* lds, const void* g) {
  __builtin_amdgcn_global_load_lds(
      (const __attribute__((address_space(1))) void*)g,
      (__attribute__((address_space(3))) void*)lds, 16, 0, 0);
}

// ---------------------------------------------------------------------------
// Fused prep (one launch, grid 32x32x6): weight transposes, RoPE table, castX
// ---------------------------------------------------------------------------
__global__ __launch_bounds__(256) void prepAll(
    const float* __restrict__ Wq, const float* __restrict__ Wk,
    const float* __restrict__ Wv, const float* __restrict__ Wo,
    const float* __restrict__ hidden, const int* __restrict__ pos_ids,
    unsigned short* __restrict__ WqkvT, unsigned short* __restrict__ WoT,
    unsigned short* __restrict__ Xb, float2* __restrict__ tab) {
  const int z = blockIdx.z;
  const int t = threadIdx.x;

  if (z == 4) {            // RoPE table
    const int idx = blockIdx.y * 32 + blockIdx.x;
    if ((t & 127) < 32) {
      const int m = idx * 2 + (t >> 7);
      const int j = t & 31;
      const float pos = (float)pos_ids[m];
      const float ang = pos * exp2f(-(float)j * (13.287712379549449f / 32.0f));
      float sn, cs;
      sincosf(ang, &sn, &cs);
      tab[(size_t)m * 32 + j] = make_float2(cs, sn);
    }
    return;
  }
  if (z == 5) {            // castX
    const size_t base = ((size_t)(blockIdx.y * 32 + blockIdx.x)) * 4096;
#pragma unroll
    for (int it = 0; it < 2; ++it) {
      const size_t i = base + it * 2048 + t * 8;
      const float4 v0 = *(const float4*)(hidden + i);
      const float4 v1 = *(const float4*)(hidden + i + 4);
      unsigned short o[8] = {f2b(v0.x), f2b(v0.y), f2b(v0.z), f2b(v0.w),
                             f2b(v1.x), f2b(v1.y), f2b(v1.z), f2b(v1.w)};
      *(bf8v*)(Xb + i) = *(bf8v*)o;
    }
    return;
  }

  const float* src;
  unsigned short* dst;
  int C;
  if (z == 0)      { src = Wq; dst = WqkvT;                      C = 2048; }
  else if (z == 1) { src = Wk; dst = WqkvT + (size_t)2048 * HID; C = 512;  }
  else if (z == 2) { src = Wv; dst = WqkvT + (size_t)2560 * HID; C = 512;  }
  else             { src = Wo; dst = WoT;                        C = 2048; }

  const int r0 = blockIdx.y * 64, c0 = blockIdx.x * 64;
  if (c0 >= C) return;
  __shared__ float T[64][65];
  {
    const int r  = t >> 2;
    const int c4 = (t & 3) * 16;
    const float* sp = src + (size_t)(r0 + r) * C + c0 + c4;
    *(float4*)&T[r][c4 + 0]  = *(const float4*)(sp + 0);
    *(float4*)&T[r][c4 + 4]  = *(const float4*)(sp + 4);
    *(float4*)&T[r][c4 + 8]  = *(const float4*)(sp + 8);
    *(float4*)&T[r][c4 + 12] = *(const float4*)(sp + 12);
  }
  __syncthreads();
  {
    const int c  = t >> 2;
    const int rr = (t & 3) * 16;
    unsigned short o[16];
#pragma unroll
    for (int i = 0; i < 16; ++i) o[i] = f2b(T[rr + i][c]);
    unsigned short* dp = dst + (size_t)(c0 + c) * HID + r0 + rr;
    *(bf8v*)dp       = *(bf8v*)&o[0];
    *(bf8v*)(dp + 8) = *(bf8v*)&o[8];
  }
}

// ===========================================================================
// GEMM core (round-17 measured best): 64x128 tile, 4 waves 2x2, BK=32,
// K=2048. Grids: QKV 768 = 3/CU exact, Wo 512 = 2/CU exact.
// T4 depth-3 (4 LDS buffers, vmcnt 6/3/0), T2 both-sides swizzle (0 conflicts).
// ===========================================================================

// ---------------------------------------------------------------------------
// QKV GEMM with fused RoPE epilogue + fused V transpose (writes Vt directly).
// ---------------------------------------------------------------------------
__global__ __launch_bounds__(256) void gemm_qkv(
    const unsigned short* __restrict__ A, const unsigned short* __restrict__ Bt,
    const float2* __restrict__ tab,
    unsigned short* __restrict__ Qb, unsigned short* __restrict__ Kb,
    unsigned short* __restrict__ Vt) {
  __shared__ unsigned short As[4][64 * 32];
  __shared__ unsigned short Bs[4][128 * 32];
  const int t  = threadIdx.x;
  const int w  = t >> 6, l = t & 63;
  const int lr = l & 15, lg = l >> 4;
  const int wr = w >> 1, wc = w & 1;
  const int bm = blockIdx.y * 64, bn = blockIdx.x * 128;

  f4v acc[2][4] = {};

  const unsigned short* Ablk = A  + (size_t)bm * HID;
  const unsigned short* Bblk = Bt + (size_t)bn * HID;
  const int srow = l >> 2;
  const int scol = (((l & 3) ^ ((srow >> 1) & 3)) * 8);
  const int rsl  = (lg ^ ((lr >> 1) & 3)) * 8;

  auto stage = [&](int buf, int k0) {
    gload16(&As[buf][(w * 16) * 32], Ablk + (size_t)(w * 16 + srow) * HID + k0 + scol);
    gload16(&Bs[buf][(w * 32)      * 32], Bblk + (size_t)(w * 32 +      srow) * HID + k0 + scol);
    gload16(&Bs[buf][(w * 32 + 16) * 32], Bblk + (size_t)(w * 32 + 16 + srow) * HID + k0 + scol);
  };

  const int nsteps = HID / 32;           // 64
  stage(0, 0);
  stage(1, 32);
  stage(2, 64);
  asm volatile("s_waitcnt vmcnt(6)" ::: "memory");   // buf0 landed
  __builtin_amdgcn_s_barrier();

  const int aoff = (wr * 32 + lr) * 32 + rsl;
  const int boff = (wc * 64 + lr) * 32 + rsl;
  for (int tt = 0; tt < nsteps; ++tt) {
    const int cur = tt & 3;
    if (tt + 3 < nsteps) stage((tt + 3) & 3, (tt + 3) * 32);

    bf8v aF[2], bF[4];
#pragma unroll
    for (int i = 0; i < 2; ++i)
      aF[i] = *(const bf8v*)&As[cur][aoff + i * 512];
#pragma unroll
    for (int j = 0; j < 4; ++j)
      bF[j] = *(const bf8v*)&Bs[cur][boff + j * 512];
    __builtin_amdgcn_s_setprio(1);
#pragma unroll
    for (int mi = 0; mi < 2; ++mi)
#pragma unroll
      for (int ni = 0; ni < 4; ++ni)
        acc[mi][ni] = __builtin_amdgcn_mfma_f32_16x16x32_bf16(aF[mi], bF[ni], acc[mi][ni], 0, 0, 0);
    __builtin_amdgcn_s_setprio(0);

    if (tt + 3 < nsteps)      { asm volatile("s_waitcnt vmcnt(6)" ::: "memory"); }
    else if (tt + 2 < nsteps) { asm volatile("s_waitcnt vmcnt(3)" ::: "memory"); }
    else                      { asm volatile("s_waitcnt vmcnt(0)" ::: "memory"); }
    __builtin_amdgcn_s_barrier();
  }

  // Fused epilogue. D layout: row = lg*4+r, col = lr (m89/m91).
  const int row0 = bm + wr * 32;
  const int colHead = bn + wc * 64;
  int mode, hh;                               // 0=Q(rope+scale) 1=K(rope) 2=V(transposed)
  if (colHead < 2048)      { mode = 0; hh = colHead >> 6;          }
  else if (colHead < 2560) { mode = 1; hh = (colHead - 2048) >> 6; }
  else                     { mode = 2; hh = (colHead - 2560) >> 6; }

#pragma unroll
  for (int mi = 0; mi < 2; ++mi)
#pragma unroll
    for (int r = 0; r < 4; ++r) {
      const int rowg = row0 + mi * 16 + lg * 4 + r;
      const int bI = rowg >> 10, s = rowg & (SS - 1);
      if (mode == 2) {
        unsigned short* base = Vt + ((size_t)(bI * NKV + hh) * 64) * SS + s;
#pragma unroll
        for (int ni = 0; ni < 4; ++ni)
          base[(size_t)(ni * 16 + lr) * SS] = f2b(acc[mi][ni][r]);
      } else {
        unsigned short* dst = (mode == 0)
            ? Qb + ((size_t)(bI * NH  + hh) * SS + s) * 64
            : Kb + ((size_t)(bI * NKV + hh) * SS + s) * 64;
        const float2 cs_lo = tab[(size_t)rowg * 32 + lr];
        const float2 cs_hi = tab[(size_t)rowg * 32 + 16 + lr];
#pragma unroll
        for (int ni = 0; ni < 4; ++ni) {
          const float2 cs = (ni & 1) ? cs_hi : cs_lo;
          const float x   = acc[mi][ni][r];
          const float prt = acc[mi][ni ^ 2][r];
          const float rh  = (ni < 2) ? -prt : prt;
          float v = x * cs.x + rh * cs.y;
          if (mode == 0) v *= 0.125f;
          dst[ni * 16 + lr] = f2b(v);
        }
      }
    }
}

// ---------------------------------------------------------------------------
// Plain bf16 GEMM for Wo (same core), f32 out. Grid (16, 32) = 512 blocks.
// ---------------------------------------------------------------------------
__global__ __launch_bounds__(256) void gemm_bf16(
    const unsigned short* __restrict__ A, const unsigned short* __restrict__ Bt,
    float* __restrict__ C, int Ndim) {
  __shared__ unsigned short As[4][64 * 32];
  __shared__ unsigned short Bs[4][128 * 32];
  const int t  = threadIdx.x;
  const int w  = t >> 6, l = t & 63;
  const int lr = l & 15, lg = l >> 4;
  const int wr = w >> 1, wc = w & 1;
  const int bm = blockIdx.y * 64, bn = blockIdx.x * 128;

  f4v acc[2][4] = {};

  const unsigned short* Ablk = A  + (size_t)bm * HID;
  const unsigned short* Bblk = Bt + (size_t)bn * HID;
  const int srow = l >> 2;
  const int scol = (((l & 3) ^ ((srow >> 1) & 3)) * 8);
  const int rsl  = (lg ^ ((lr >> 1) & 3)) * 8;

  auto stage = [&](int buf, int k0) {
    gload16(&As[buf][(w * 16) * 32], Ablk + (size_t)(w * 16 + srow) * HID + k0 + scol);
    gload16(&Bs[buf][(w * 32)      * 32], Bblk + (size_t)(w * 32 +      srow) * HID + k0 + scol);
    gload16(&Bs[buf][(w * 32 + 16) * 32], Bblk + (size_t)(w * 32 + 16 + srow) * HID + k0 + scol);
  };

  const int nsteps = HID / 32;
  stage(0, 0);
  stage(1, 32);
  stage(2, 64);
  asm volatile("s_waitcnt vmcnt(6)" ::: "memory");
  __builtin_amdgcn_s_barrier();

  const int aoff = (wr * 32 + lr) * 32 + rsl;
  const int boff = (wc * 64 + lr) * 32 + rsl;
  for (int tt = 0; tt < nsteps; ++tt) {
    const int cur = tt & 3;
    if (tt + 3 < nsteps) stage((tt + 3) & 3, (tt + 3) * 32);

    bf8v aF[2], bF[4];
#pragma unroll
    for (int i = 0; i < 2; ++i)
      aF[i] = *(const bf8v*)&As[cur][aoff + i * 512];
#pragma unroll
    for (int j = 0; j < 4; ++j)
      bF[j] = *(const bf8v*)&Bs[cur][boff + j * 512];
    __builtin_amdgcn_s_setprio(1);
#pragma unroll
    for (int mi = 0; mi < 2; ++mi)
#pragma unroll
      for (int ni = 0; ni < 4; ++ni)
        acc[mi][ni] = __builtin_amdgcn_mfma_f32_16x16x32_bf16(aF[mi], bF[ni], acc[mi][ni], 0, 0, 0);
    __builtin_amdgcn_s_setprio(0);

    if (tt + 3 < nsteps)      { asm volatile("s_waitcnt vmcnt(6)" ::: "memory"); }
    else if (tt + 2 < nsteps) { asm volatile("s_waitcnt vmcnt(3)" ::: "memory"); }
    else                      { asm volatile("s_waitcnt vmcnt(0)" ::: "memory"); }
    __builtin_amdgcn_s_barrier();
  }

  const int row0 = bm + wr * 32;
  const int col0 = bn + wc * 64;
#pragma unroll
  for (int mi = 0; mi < 2; ++mi)
#pragma unroll
    for (int r = 0; r < 4; ++r) {
      const size_t rowoff = (size_t)(row0 + mi * 16 + lg * 4 + r) * Ndim;
#pragma unroll
      for (int ni = 0; ni < 4; ++ni)
        C[rowoff + col0 + ni * 16 + lr] = acc[mi][ni][r];
    }
}

// ---------------------------------------------------------------------------
// Flash attention (round-11 structure) + K-PREFETCH: K(i+1) is loaded into
// registers right after QK^T(i) consumes K(i) — load-to-use distance becomes
// a full iteration (~2000cy) instead of inline (~200cy L2 latency exposed).
// V keeps the T14 reg-stage. KVBLK=64, 2-wave blocks, paired {xb, 31-xb}.
// ---------------------------------------------------------------------------
__global__ __launch_bounds__(128) void attn_mfma(
    const unsigned short* __restrict__ Qb, const unsigned short* __restrict__ Kb,
    const unsigned short* __restrict__ Vt, unsigned short* __restrict__ attn) {
  const int xb = blockIdx.x;
  const int h = blockIdx.y, b = blockIdx.z;
  const int kv = h >> 2;
  const int w  = threadIdx.x >> 6;
  const int l  = threadIdx.x & 63;
  const int lr = l & 15;
  const int lg = l >> 4;
  const int t  = threadIdx.x;

  __shared__ unsigned short VT[64][72];
  __shared__ unsigned short PL[2][16][72];

  const unsigned short* Kp = Kb + ((size_t)((b * NKV + kv) * SS)) * 64;
  const unsigned short* Vp = Vt + ((size_t)((b * NKV + kv) * 64)) * SS;

  const int vd  = t >> 1;
  const int vso = (t & 1) * 32;

  for (int half = 0; half < 2; ++half) {
    const int qt = half ? (31 - xb) : xb;
    const int qbase = qt * 32;
    const int qW = qbase + w * 16;
    const unsigned short* Qp = Qb + ((size_t)((b * NH + h) * SS + qW)) * 64;
    bf8v aQ0 = *(const bf8v*)(Qp + (size_t)lr * 64 + lg * 8);
    bf8v aQ1 = *(const bf8v*)(Qp + (size_t)lr * 64 + 32 + lg * 8);

    f4v o[4] = {{0,0,0,0},{0,0,0,0},{0,0,0,0},{0,0,0,0}};
    float lsumL[4] = {0.f, 0.f, 0.f, 0.f};

    // K prologue: load tile 0 fragments into registers
    bf8v kc[8];
#pragma unroll
    for (int c = 0; c < 4; ++c) {
      const unsigned short* kr = Kp + (size_t)(c * 16 + lr) * 64 + lg * 8;
      kc[2 * c]     = *(const bf8v*)(kr);
      kc[2 * c + 1] = *(const bf8v*)(kr + 32);
    }

    for (int kvb = 0; kvb < qbase + 32; kvb += 64) {
      __syncthreads();
      // V(i) reg-stage (T14)
      const unsigned short* vp = Vp + (size_t)vd * SS + kvb + vso;
      const bf8v v0 = *(const bf8v*)(vp);
      const bf8v v1 = *(const bf8v*)(vp + 8);
      const bf8v v2 = *(const bf8v*)(vp + 16);
      const bf8v v3 = *(const bf8v*)(vp + 24);

      // QK^T from prefetched K registers
      f4v sc[4] = {{0,0,0,0},{0,0,0,0},{0,0,0,0},{0,0,0,0}};
      __builtin_amdgcn_s_setprio(1);
#pragma unroll
      for (int c = 0; c < 4; ++c) {
        sc[c] = __builtin_amdgcn_mfma_f32_16x16x32_bf16(aQ0, kc[2 * c],     sc[c], 0, 0, 0);
        sc[c] = __builtin_amdgcn_mfma_f32_16x16x32_bf16(aQ1, kc[2 * c + 1], sc[c], 0, 0, 0);
      }
      __builtin_amdgcn_s_setprio(0);

      // Prefetch K(i+1) — lands during softmax + barrier + PV
      if (kvb + 64 < qbase + 32) {
#pragma unroll
        for (int c = 0; c < 4; ++c) {
          const unsigned short* kr = Kp + (size_t)(kvb + 64 + c * 16 + lr) * 64 + lg * 8;
          kc[2 * c]     = *(const bf8v*)(kr);
          kc[2 * c + 1] = *(const bf8v*)(kr + 32);
        }
      }

      // P = exp(S) (no max tracking; scores bounded, softmax-invariant)
#pragma unroll
      for (int r = 0; r < 4; ++r) {
        const int qrow = qW + lg * 4 + r;
        float ps = 0.f;
        unsigned short pb[4];
#pragma unroll
        for (int c = 0; c < 4; ++c) {
          const float s = ((kvb + c * 16 + lr) > qrow) ? -INFINITY : sc[c][r];
          const float p = __expf(s);
          ps += p;
          pb[c] = f2b(p);
        }
        lsumL[r] += ps;
#pragma unroll
        for (int c = 0; c < 4; ++c) PL[w][lg * 4 + r][c * 16 + lr] = pb[c];
      }

      // staged V -> LDS
      *(bf8v*)&VT[vd][vso]      = v0;
      *(bf8v*)&VT[vd][vso + 8]  = v1;
      *(bf8v*)&VT[vd][vso + 16] = v2;
      *(bf8v*)&VT[vd][vso + 24] = v3;

      __syncthreads();

      // O += P V
      bf8v aP0 = *(const bf8v*)&PL[w][lr][lg * 8];
      bf8v aP1 = *(const bf8v*)&PL[w][lr][32 + lg * 8];
      __builtin_amdgcn_s_setprio(1);
#pragma unroll
      for (int n = 0; n < 4; ++n) {
        bf8v bV0 = *(const bf8v*)&VT[n * 16 + lr][lg * 8];
        bf8v bV1 = *(const bf8v*)&VT[n * 16 + lr][32 + lg * 8];
        o[n] = __builtin_amdgcn_mfma_f32_16x16x32_bf16(aP0, bV0, o[n], 0, 0, 0);
        o[n] = __builtin_amdgcn_mfma_f32_16x16x32_bf16(aP1, bV1, o[n], 0, 0, 0);
      }
      __builtin_amdgcn_s_setprio(0);
    }

#pragma unroll
    for (int r = 0; r < 4; ++r) {
      float ls = lsumL[r];
      ls += __shfl_xor(ls, 1);
      ls += __shfl_xor(ls, 2);
      ls += __shfl_xor(ls, 4);
      ls += __shfl_xor(ls, 8);
      const float inv = 1.0f / ls;
      const int row = qW + lg * 4 + r;
      unsigned short* dst = attn + (size_t)(b * SS + row) * HID + h * 64;
#pragma unroll
      for (int n = 0; n < 4; ++n) dst[n * 16 + lr] = f2b(o[n][r] * inv);
    }
  }
}

// ---------------------------------------------------------------------------
extern "C" void kernel_launch(void* const* d_in, const int* in_sizes, int n_in,
                              void* d_out, int out_size, void* d_ws, size_t ws_size,
                              hipStream_t stream) {
  const float* hidden = (const float*)d_in[0];
  const int*   pos    = (const int*)d_in[1];
  const float* Wq = (const float*)d_in[3];
  const float* Wk = (const float*)d_in[4];
  const float* Wv = (const float*)d_in[5];
  const float* Wo = (const float*)d_in[6];
  float* out = (float*)d_out;

  char* ws = (char*)d_ws;
  unsigned short* WqkvT = (unsigned short*)(ws);              // 12 MB  [3072][2048]
  unsigned short* WoT   = (unsigned short*)(ws + 12582912);   //  8 MB  [2048][2048]
  unsigned short* Xb    = (unsigned short*)(ws + 20971520);   //  8 MB  [M][2048]
  unsigned short* attnb = Xb;                                 // alias (Xb dead after gemm_qkv)
  unsigned short* Qb    = (unsigned short*)(ws + 29360128);   //  8 MB  [B][NH][S][64]
  unsigned short* Kb    = (unsigned short*)(ws + 37748736);   //  2 MB  [B][NKV][S][64]
  unsigned short* Vt    = (unsigned short*)(ws + 39845888);   //  2 MB  [B*NKV][64][S]
  float2*         tab   = (float2*)(ws + 41943040);           // 512 KB [M][32]

  dim3 blk(256);

  prepAll<<<dim3(32, 32, 6), blk, 0, stream>>>(Wq, Wk, Wv, Wo, hidden, pos,
                                               WqkvT, WoT, Xb, tab);

  // QKV: 24 x 32 = 768 blocks = 3 blocks/CU exact; V written transposed
  gemm_qkv<<<dim3(NQKV / 128, M / 64), blk, 0, stream>>>(Xb, WqkvT, tab, Qb, Kb, Vt);

  attn_mfma<<<dim3(16, NH, BB), dim3(128), 0, stream>>>(Qb, Kb, Vt, attnb);

  // Wo: 16 x 32 = 512 blocks = 2 blocks/CU exact
  gemm_bf16<<<dim3(HID / 128, M / 64), blk, 0, stream>>>(attnb, WoT, out, HID);
}

// Round 22
// 148.540 us; speedup vs baseline: 1.1737x; 1.0039x over previous
//
#include <hip/hip_runtime.h>
#include <hip/hip_bf16.h>
#include <math.h>

// Problem constants
constexpr int BB   = 2;
constexpr int SS   = 1024;
constexpr int HID  = 2048;
constexpr int NH   = 32;
constexpr int NKV  = 8;
constexpr int HD   = 64;
constexpr int M    = BB * SS;          // 2048 rows
constexpr int NQKV = 3072;             // fused q|k|v output width

typedef __attribute__((ext_vector_type(8))) short bf8v;   // 8 bf16
typedef __attribute__((ext_vector_type(4))) float f4v;    // 4 f32 acc

static __device__ __forceinline__ unsigned short f2b(float x) {
  __hip_bfloat16 h = __float2bfloat16(x);
  return *reinterpret_cast<unsigned short*>(&h);
}
static __device__ __forceinline__ void gload16(void* lds, const void* g) {
  __builtin_amdgcn_global_load_lds(
      (const __attribute__((address_space(1))) void*)g,
      (__attribute__((address_space(3))) void*)lds, 16, 0, 0);
}

// ---------------------------------------------------------------------------
// Fused prep (one launch, grid 32x32x6): weight transposes, RoPE table, castX
// ---------------------------------------------------------------------------
__global__ __launch_bounds__(256) void prepAll(
    const float* __restrict__ Wq, const float* __restrict__ Wk,
    const float* __restrict__ Wv, const float* __restrict__ Wo,
    const float* __restrict__ hidden, const int* __restrict__ pos_ids,
    unsigned short* __restrict__ WqkvT, unsigned short* __restrict__ WoT,
    unsigned short* __restrict__ Xb, float2* __restrict__ tab) {
  const int z = blockIdx.z;
  const int t = threadIdx.x;

  if (z == 4) {            // RoPE table
    const int idx = blockIdx.y * 32 + blockIdx.x;
    if ((t & 127) < 32) {
      const int m = idx * 2 + (t >> 7);
      const int j = t & 31;
      const float pos = (float)pos_ids[m];
      const float ang = pos * exp2f(-(float)j * (13.287712379549449f / 32.0f));
      float sn, cs;
      sincosf(ang, &sn, &cs);
      tab[(size_t)m * 32 + j] = make_float2(cs, sn);
    }
    return;
  }
  if (z == 5) {            // castX
    const size_t base = ((size_t)(blockIdx.y * 32 + blockIdx.x)) * 4096;
#pragma unroll
    for (int it = 0; it < 2; ++it) {
      const size_t i = base + it * 2048 + t * 8;
      const float4 v0 = *(const float4*)(hidden + i);
      const float4 v1 = *(const float4*)(hidden + i + 4);
      unsigned short o[8] = {f2b(v0.x), f2b(v0.y), f2b(v0.z), f2b(v0.w),
                             f2b(v1.x), f2b(v1.y), f2b(v1.z), f2b(v1.w)};
      *(bf8v*)(Xb + i) = *(bf8v*)o;
    }
    return;
  }

  const float* src;
  unsigned short* dst;
  int C;
  if (z == 0)      { src = Wq; dst = WqkvT;                      C = 2048; }
  else if (z == 1) { src = Wk; dst = WqkvT + (size_t)2048 * HID; C = 512;  }
  else if (z == 2) { src = Wv; dst = WqkvT + (size_t)2560 * HID; C = 512;  }
  else             { src = Wo; dst = WoT;                        C = 2048; }

  const int r0 = blockIdx.y * 64, c0 = blockIdx.x * 64;
  if (c0 >= C) return;
  __shared__ float T[64][65];
  {
    const int r  = t >> 2;
    const int c4 = (t & 3) * 16;
    const float* sp = src + (size_t)(r0 + r) * C + c0 + c4;
    *(float4*)&T[r][c4 + 0]  = *(const float4*)(sp + 0);
    *(float4*)&T[r][c4 + 4]  = *(const float4*)(sp + 4);
    *(float4*)&T[r][c4 + 8]  = *(const float4*)(sp + 8);
    *(float4*)&T[r][c4 + 12] = *(const float4*)(sp + 12);
  }
  __syncthreads();
  {
    const int c  = t >> 2;
    const int rr = (t & 3) * 16;
    unsigned short o[16];
#pragma unroll
    for (int i = 0; i < 16; ++i) o[i] = f2b(T[rr + i][c]);
    unsigned short* dp = dst + (size_t)(c0 + c) * HID + r0 + rr;
    *(bf8v*)dp       = *(bf8v*)&o[0];
    *(bf8v*)(dp + 8) = *(bf8v*)&o[8];
  }
}

// ===========================================================================
// GEMM core v2: 64x128 tile, *8 waves* (512 threads, 4M x 2N; each wave a
// 16x64 sub-tile = 4 MFMA/step). Same tile/traffic/LDS as the round-17 best,
// but waves/SIMD doubles (QKV: 6/SIMD, Wo: 4/SIMD) — attacks the measured
// ~58% idle (MfmaUtil 18 + VALUBusy 24) via more TLP at fixed traffic.
// T4 depth-3: 4 LDS buffers (48KB); staging split: waves 0-3 load 1 A-unit +
// 1 B-unit (16 rows each), waves 4-7 load 1 B-unit; per-wave counted vmcnt
// (4/2/0 for 2-load waves, 2/1/0 for 1-load waves) across raw barriers.
// T2 both-sides 16B-slot swizzle (0 conflicts, r16-verified).
// ===========================================================================

// ---------------------------------------------------------------------------
// QKV GEMM with fused RoPE epilogue + fused V transpose. Grid (24,32)=768,
// 512 threads: 3 blocks/CU exact = 24 waves/CU.
// ---------------------------------------------------------------------------
__global__ __launch_bounds__(512) void gemm_qkv(
    const unsigned short* __restrict__ A, const unsigned short* __restrict__ Bt,
    const float2* __restrict__ tab,
    unsigned short* __restrict__ Qb, unsigned short* __restrict__ Kb,
    unsigned short* __restrict__ Vt) {
  __shared__ unsigned short As[4][64 * 32];
  __shared__ unsigned short Bs[4][128 * 32];
  const int t  = threadIdx.x;
  const int w  = t >> 6, l = t & 63;     // w: 0..7
  const int lr = l & 15, lg = l >> 4;
  const int wr = w >> 1, wc = w & 1;     // wr: 0..3 (M), wc: 0..1 (N)
  const int bm = blockIdx.y * 64, bn = blockIdx.x * 128;

  f4v acc[4] = {};

  const unsigned short* Ablk = A  + (size_t)bm * HID;
  const unsigned short* Bblk = Bt + (size_t)bn * HID;
  const int srow = l >> 2;
  const int scol = (((l & 3) ^ ((srow >> 1) & 3)) * 8);
  const int rsl  = (lg ^ ((lr >> 1) & 3)) * 8;

  auto stage = [&](int buf, int k0) {
    if (w < 4) {   // A-unit w (rows w*16..) + B-unit w
      gload16(&As[buf][(w * 16) * 32], Ablk + (size_t)(w * 16 + srow) * HID + k0 + scol);
      gload16(&Bs[buf][(w * 16) * 32], Bblk + (size_t)(w * 16 + srow) * HID + k0 + scol);
    } else {       // B-unit w (rows w*16..)
      gload16(&Bs[buf][(w * 16) * 32], Bblk + (size_t)(w * 16 + srow) * HID + k0 + scol);
    }
  };

  const int nsteps = HID / 32;           // 64
  stage(0, 0);
  stage(1, 32);
  stage(2, 64);
  if (w < 4) { asm volatile("s_waitcnt vmcnt(4)" ::: "memory"); }
  else       { asm volatile("s_waitcnt vmcnt(2)" ::: "memory"); }
  __builtin_amdgcn_s_barrier();

  const int aoff = (wr * 16 + lr) * 32 + rsl;
  const int boff = (wc * 64 + lr) * 32 + rsl;
  for (int tt = 0; tt < nsteps; ++tt) {
    const int cur = tt & 3;
    if (tt + 3 < nsteps) stage((tt + 3) & 3, (tt + 3) * 32);

    bf8v aF = *(const bf8v*)&As[cur][aoff];
    bf8v bF[4];
#pragma unroll
    for (int j = 0; j < 4; ++j)
      bF[j] = *(const bf8v*)&Bs[cur][boff + j * 512];
    __builtin_amdgcn_s_setprio(1);
#pragma unroll
    for (int ni = 0; ni < 4; ++ni)
      acc[ni] = __builtin_amdgcn_mfma_f32_16x16x32_bf16(aF, bF[ni], acc[ni], 0, 0, 0);
    __builtin_amdgcn_s_setprio(0);

    if (tt + 3 < nsteps) {
      if (w < 4) { asm volatile("s_waitcnt vmcnt(4)" ::: "memory"); }
      else       { asm volatile("s_waitcnt vmcnt(2)" ::: "memory"); }
    } else if (tt + 2 < nsteps) {
      if (w < 4) { asm volatile("s_waitcnt vmcnt(2)" ::: "memory"); }
      else       { asm volatile("s_waitcnt vmcnt(1)" ::: "memory"); }
    } else {
      asm volatile("s_waitcnt vmcnt(0)" ::: "memory");
    }
    __builtin_amdgcn_s_barrier();
  }

  // Fused epilogue. D layout: row = lg*4+r, col = lr (m89/m91).
  const int row0 = bm + wr * 16;
  const int colHead = bn + wc * 64;
  int mode, hh;                               // 0=Q(rope+scale) 1=K(rope) 2=V(transposed)
  if (colHead < 2048)      { mode = 0; hh = colHead >> 6;          }
  else if (colHead < 2560) { mode = 1; hh = (colHead - 2048) >> 6; }
  else                     { mode = 2; hh = (colHead - 2560) >> 6; }

#pragma unroll
  for (int r = 0; r < 4; ++r) {
    const int rowg = row0 + lg * 4 + r;
    const int bI = rowg >> 10, s = rowg & (SS - 1);
    if (mode == 2) {
      unsigned short* base = Vt + ((size_t)(bI * NKV + hh) * 64) * SS + s;
#pragma unroll
      for (int ni = 0; ni < 4; ++ni)
        base[(size_t)(ni * 16 + lr) * SS] = f2b(acc[ni][r]);
    } else {
      unsigned short* dst = (mode == 0)
          ? Qb + ((size_t)(bI * NH  + hh) * SS + s) * 64
          : Kb + ((size_t)(bI * NKV + hh) * SS + s) * 64;
      const float2 cs_lo = tab[(size_t)rowg * 32 + lr];
      const float2 cs_hi = tab[(size_t)rowg * 32 + 16 + lr];
#pragma unroll
      for (int ni = 0; ni < 4; ++ni) {
        const float2 cs = (ni & 1) ? cs_hi : cs_lo;
        const float x   = acc[ni][r];
        const float prt = acc[ni ^ 2][r];
        const float rh  = (ni < 2) ? -prt : prt;
        float v = x * cs.x + rh * cs.y;
        if (mode == 0) v *= 0.125f;
        dst[ni * 16 + lr] = f2b(v);
      }
    }
  }
}

// ---------------------------------------------------------------------------
// Plain bf16 GEMM for Wo (same 8-wave core), f32 out. Grid (16,32)=512,
// 512 threads: 2 blocks/CU exact = 16 waves/CU.
// ---------------------------------------------------------------------------
__global__ __launch_bounds__(512) void gemm_bf16(
    const unsigned short* __restrict__ A, const unsigned short* __restrict__ Bt,
    float* __restrict__ C, int Ndim) {
  __shared__ unsigned short As[4][64 * 32];
  __shared__ unsigned short Bs[4][128 * 32];
  const int t  = threadIdx.x;
  const int w  = t >> 6, l = t & 63;
  const int lr = l & 15, lg = l >> 4;
  const int wr = w >> 1, wc = w & 1;
  const int bm = blockIdx.y * 64, bn = blockIdx.x * 128;

  f4v acc[4] = {};

  const unsigned short* Ablk = A  + (size_t)bm * HID;
  const unsigned short* Bblk = Bt + (size_t)bn * HID;
  const int srow = l >> 2;
  const int scol = (((l & 3) ^ ((srow >> 1) & 3)) * 8);
  const int rsl  = (lg ^ ((lr >> 1) & 3)) * 8;

  auto stage = [&](int buf, int k0) {
    if (w < 4) {
      gload16(&As[buf][(w * 16) * 32], Ablk + (size_t)(w * 16 + srow) * HID + k0 + scol);
      gload16(&Bs[buf][(w * 16) * 32], Bblk + (size_t)(w * 16 + srow) * HID + k0 + scol);
    } else {
      gload16(&Bs[buf][(w * 16) * 32], Bblk + (size_t)(w * 16 + srow) * HID + k0 + scol);
    }
  };

  const int nsteps = HID / 32;
  stage(0, 0);
  stage(1, 32);
  stage(2, 64);
  if (w < 4) { asm volatile("s_waitcnt vmcnt(4)" ::: "memory"); }
  else       { asm volatile("s_waitcnt vmcnt(2)" ::: "memory"); }
  __builtin_amdgcn_s_barrier();

  const int aoff = (wr * 16 + lr) * 32 + rsl;
  const int boff = (wc * 64 + lr) * 32 + rsl;
  for (int tt = 0; tt < nsteps; ++tt) {
    const int cur = tt & 3;
    if (tt + 3 < nsteps) stage((tt + 3) & 3, (tt + 3) * 32);

    bf8v aF = *(const bf8v*)&As[cur][aoff];
    bf8v bF[4];
#pragma unroll
    for (int j = 0; j < 4; ++j)
      bF[j] = *(const bf8v*)&Bs[cur][boff + j * 512];
    __builtin_amdgcn_s_setprio(1);
#pragma unroll
    for (int ni = 0; ni < 4; ++ni)
      acc[ni] = __builtin_amdgcn_mfma_f32_16x16x32_bf16(aF, bF[ni], acc[ni], 0, 0, 0);
    __builtin_amdgcn_s_setprio(0);

    if (tt + 3 < nsteps) {
      if (w < 4) { asm volatile("s_waitcnt vmcnt(4)" ::: "memory"); }
      else       { asm volatile("s_waitcnt vmcnt(2)" ::: "memory"); }
    } else if (tt + 2 < nsteps) {
      if (w < 4) { asm volatile("s_waitcnt vmcnt(2)" ::: "memory"); }
      else       { asm volatile("s_waitcnt vmcnt(1)" ::: "memory"); }
    } else {
      asm volatile("s_waitcnt vmcnt(0)" ::: "memory");
    }
    __builtin_amdgcn_s_barrier();
  }

  const int row0 = bm + wr * 16;
  const int col0 = bn + wc * 64;
#pragma unroll
  for (int r = 0; r < 4; ++r) {
    const size_t rowoff = (size_t)(row0 + lg * 4 + r) * Ndim;
#pragma unroll
    for (int ni = 0; ni < 4; ++ni)
      C[rowoff + col0 + ni * 16 + lr] = acc[ni][r];
  }
}

// ---------------------------------------------------------------------------
// Flash attention (round-21 best: K-prefetch + T14 V-stage + no-max softmax).
// ---------------------------------------------------------------------------
__global__ __launch_bounds__(128) void attn_mfma(
    const unsigned short* __restrict__ Qb, const unsigned short* __restrict__ Kb,
    const unsigned short* __restrict__ Vt, unsigned short* __restrict__ attn) {
  const int xb = blockIdx.x;
  const int h = blockIdx.y, b = blockIdx.z;
  const int kv = h >> 2;
  const int w  = threadIdx.x >> 6;
  const int l  = threadIdx.x & 63;
  const int lr = l & 15;
  const int lg = l >> 4;
  const int t  = threadIdx.x;

  __shared__ unsigned short VT[64][72];
  __shared__ unsigned short PL[2][16][72];

  const unsigned short* Kp = Kb + ((size_t)((b * NKV + kv) * SS)) * 64;
  const unsigned short* Vp = Vt + ((size_t)((b * NKV + kv) * 64)) * SS;

  const int vd  = t >> 1;
  const int vso = (t & 1) * 32;

  for (int half = 0; half < 2; ++half) {
    const int qt = half ? (31 - xb) : xb;
    const int qbase = qt * 32;
    const int qW = qbase + w * 16;
    const unsigned short* Qp = Qb + ((size_t)((b * NH + h) * SS + qW)) * 64;
    bf8v aQ0 = *(const bf8v*)(Qp + (size_t)lr * 64 + lg * 8);
    bf8v aQ1 = *(const bf8v*)(Qp + (size_t)lr * 64 + 32 + lg * 8);

    f4v o[4] = {{0,0,0,0},{0,0,0,0},{0,0,0,0},{0,0,0,0}};
    float lsumL[4] = {0.f, 0.f, 0.f, 0.f};

    bf8v kc[8];
#pragma unroll
    for (int c = 0; c < 4; ++c) {
      const unsigned short* kr = Kp + (size_t)(c * 16 + lr) * 64 + lg * 8;
      kc[2 * c]     = *(const bf8v*)(kr);
      kc[2 * c + 1] = *(const bf8v*)(kr + 32);
    }

    for (int kvb = 0; kvb < qbase + 32; kvb += 64) {
      __syncthreads();
      const unsigned short* vp = Vp + (size_t)vd * SS + kvb + vso;
      const bf8v v0 = *(const bf8v*)(vp);
      const bf8v v1 = *(const bf8v*)(vp + 8);
      const bf8v v2 = *(const bf8v*)(vp + 16);
      const bf8v v3 = *(const bf8v*)(vp + 24);

      f4v sc[4] = {{0,0,0,0},{0,0,0,0},{0,0,0,0},{0,0,0,0}};
      __builtin_amdgcn_s_setprio(1);
#pragma unroll
      for (int c = 0; c < 4; ++c) {
        sc[c] = __builtin_amdgcn_mfma_f32_16x16x32_bf16(aQ0, kc[2 * c],     sc[c], 0, 0, 0);
        sc[c] = __builtin_amdgcn_mfma_f32_16x16x32_bf16(aQ1, kc[2 * c + 1], sc[c], 0, 0, 0);
      }
      __builtin_amdgcn_s_setprio(0);

      if (kvb + 64 < qbase + 32) {
#pragma unroll
        for (int c = 0; c < 4; ++c) {
          const unsigned short* kr = Kp + (size_t)(kvb + 64 + c * 16 + lr) * 64 + lg * 8;
          kc[2 * c]     = *(const bf8v*)(kr);
          kc[2 * c + 1] = *(const bf8v*)(kr + 32);
        }
      }

#pragma unroll
      for (int r = 0; r < 4; ++r) {
        const int qrow = qW + lg * 4 + r;
        float ps = 0.f;
        unsigned short pb[4];
#pragma unroll
        for (int c = 0; c < 4; ++c) {
          const float s = ((kvb + c * 16 + lr) > qrow) ? -INFINITY : sc[c][r];
          const float p = __expf(s);
          ps += p;
          pb[c] = f2b(p);
        }
        lsumL[r] += ps;
#pragma unroll
        for (int c = 0; c < 4; ++c) PL[w][lg * 4 + r][c * 16 + lr] = pb[c];
      }

      *(bf8v*)&VT[vd][vso]      = v0;
      *(bf8v*)&VT[vd][vso + 8]  = v1;
      *(bf8v*)&VT[vd][vso + 16] = v2;
      *(bf8v*)&VT[vd][vso + 24] = v3;

      __syncthreads();

      bf8v aP0 = *(const bf8v*)&PL[w][lr][lg * 8];
      bf8v aP1 = *(const bf8v*)&PL[w][lr][32 + lg * 8];
      __builtin_amdgcn_s_setprio(1);
#pragma unroll
      for (int n = 0; n < 4; ++n) {
        bf8v bV0 = *(const bf8v*)&VT[n * 16 + lr][lg * 8];
        bf8v bV1 = *(const bf8v*)&VT[n * 16 + lr][32 + lg * 8];
        o[n] = __builtin_amdgcn_mfma_f32_16x16x32_bf16(aP0, bV0, o[n], 0, 0, 0);
        o[n] = __builtin_amdgcn_mfma_f32_16x16x32_bf16(aP1, bV1, o[n], 0, 0, 0);
      }
      __builtin_amdgcn_s_setprio(0);
    }

#pragma unroll
    for (int r = 0; r < 4; ++r) {
      float ls = lsumL[r];
      ls += __shfl_xor(ls, 1);
      ls += __shfl_xor(ls, 2);
      ls += __shfl_xor(ls, 4);
      ls += __shfl_xor(ls, 8);
      const float inv = 1.0f / ls;
      const int row = qW + lg * 4 + r;
      unsigned short* dst = attn + (size_t)(b * SS + row) * HID + h * 64;
#pragma unroll
      for (int n = 0; n < 4; ++n) dst[n * 16 + lr] = f2b(o[n][r] * inv);
    }
  }
}

// ---------------------------------------------------------------------------
extern "C" void kernel_launch(void* const* d_in, const int* in_sizes, int n_in,
                              void* d_out, int out_size, void* d_ws, size_t ws_size,
                              hipStream_t stream) {
  const float* hidden = (const float*)d_in[0];
  const int*   pos    = (const int*)d_in[1];
  const float* Wq = (const float*)d_in[3];
  const float* Wk = (const float*)d_in[4];
  const float* Wv = (const float*)d_in[5];
  const float* Wo = (const float*)d_in[6];
  float* out = (float*)d_out;

  char* ws = (char*)d_ws;
  unsigned short* WqkvT = (unsigned short*)(ws);              // 12 MB  [3072][2048]
  unsigned short* WoT   = (unsigned short*)(ws + 12582912);   //  8 MB  [2048][2048]
  unsigned short* Xb    = (unsigned short*)(ws + 20971520);   //  8 MB  [M][2048]
  unsigned short* attnb = Xb;                                 // alias (Xb dead after gemm_qkv)
  unsigned short* Qb    = (unsigned short*)(ws + 29360128);   //  8 MB  [B][NH][S][64]
  unsigned short* Kb    = (unsigned short*)(ws + 37748736);   //  2 MB  [B][NKV][S][64]
  unsigned short* Vt    = (unsigned short*)(ws + 39845888);   //  2 MB  [B*NKV][64][S]
  float2*         tab   = (float2*)(ws + 41943040);           // 512 KB [M][32]

  dim3 blk(256);

  prepAll<<<dim3(32, 32, 6), blk, 0, stream>>>(Wq, Wk, Wv, Wo, hidden, pos,
                                               WqkvT, WoT, Xb, tab);

  // QKV: 768 blocks x 512 threads = 3 blocks/CU exact (24 waves/CU)
  gemm_qkv<<<dim3(NQKV / 128, M / 64), dim3(512), 0, stream>>>(Xb, WqkvT, tab, Qb, Kb, Vt);

  attn_mfma<<<dim3(16, NH, BB), dim3(128), 0, stream>>>(Qb, Kb, Vt, attnb);

  // Wo: 512 blocks x 512 threads = 2 blocks/CU exact (16 waves/CU)
  gemm_bf16<<<dim3(HID / 128, M / 64), dim3(512), 0, stream>>>(attnb, WoT, out, HID);
}

// Round 23
// 131.993 us; speedup vs baseline: 1.3209x; 1.1254x over previous
//
#include <hip/hip_runtime.h>
#include <hip/hip_bf16.h>
#include <math.h>

// Problem constants
constexpr int BB   = 2;
constexpr int SS   = 1024;
constexpr int HID  = 2048;
constexpr int NH   = 32;
constexpr int NKV  = 8;
constexpr int HD   = 64;
constexpr int M    = BB * SS;          // 2048 rows
constexpr int NQKV = 3072;             // fused q|k|v output width

typedef __attribute__((ext_vector_type(8))) short bf8v;   // 8 bf16
typedef __attribute__((ext_vector_type(4))) float f4v;    // 4 f32 acc

static __device__ __forceinline__ unsigned short f2b(float x) {
  __hip_bfloat16 h = __float2bfloat16(x);
  return *reinterpret_cast<unsigned short*>(&h);
}
static __device__ __forceinline__ void gload16(void* lds, const void* g) {
  __builtin_amdgcn_global_load_lds(
      (const __attribute__((address_space(1))) void*)g,
      (__attribute__((address_space(3))) void*)lds, 16, 0, 0);
}

// ---------------------------------------------------------------------------
// Fused prep (one launch, grid 32x32x6): weight transposes, RoPE table, castX
// ---------------------------------------------------------------------------
__global__ __launch_bounds__(256) void prepAll(
    const float* __restrict__ Wq, const float* __restrict__ Wk,
    const float* __restrict__ Wv, const float* __restrict__ Wo,
    const float* __restrict__ hidden, const int* __restrict__ pos_ids,
    unsigned short* __restrict__ WqkvT, unsigned short* __restrict__ WoT,
    unsigned short* __restrict__ Xb, float2* __restrict__ tab) {
  const int z = blockIdx.z;
  const int t = threadIdx.x;

  if (z == 4) {            // RoPE table
    const int idx = blockIdx.y * 32 + blockIdx.x;
    if ((t & 127) < 32) {
      const int m = idx * 2 + (t >> 7);
      const int j = t & 31;
      const float pos = (float)pos_ids[m];
      const float ang = pos * exp2f(-(float)j * (13.287712379549449f / 32.0f));
      float sn, cs;
      sincosf(ang, &sn, &cs);
      tab[(size_t)m * 32 + j] = make_float2(cs, sn);
    }
    return;
  }
  if (z == 5) {            // castX
    const size_t base = ((size_t)(blockIdx.y * 32 + blockIdx.x)) * 4096;
#pragma unroll
    for (int it = 0; it < 2; ++it) {
      const size_t i = base + it * 2048 + t * 8;
      const float4 v0 = *(const float4*)(hidden + i);
      const float4 v1 = *(const float4*)(hidden + i + 4);
      unsigned short o[8] = {f2b(v0.x), f2b(v0.y), f2b(v0.z), f2b(v0.w),
                             f2b(v1.x), f2b(v1.y), f2b(v1.z), f2b(v1.w)};
      *(bf8v*)(Xb + i) = *(bf8v*)o;
    }
    return;
  }

  const float* src;
  unsigned short* dst;
  int C;
  if (z == 0)      { src = Wq; dst = WqkvT;                      C = 2048; }
  else if (z == 1) { src = Wk; dst = WqkvT + (size_t)2048 * HID; C = 512;  }
  else if (z == 2) { src = Wv; dst = WqkvT + (size_t)2560 * HID; C = 512;  }
  else             { src = Wo; dst = WoT;                        C = 2048; }

  const int r0 = blockIdx.y * 64, c0 = blockIdx.x * 64;
  if (c0 >= C) return;
  __shared__ float T[64][65];
  {
    const int r  = t >> 2;
    const int c4 = (t & 3) * 16;
    const float* sp = src + (size_t)(r0 + r) * C + c0 + c4;
    *(float4*)&T[r][c4 + 0]  = *(const float4*)(sp + 0);
    *(float4*)&T[r][c4 + 4]  = *(const float4*)(sp + 4);
    *(float4*)&T[r][c4 + 8]  = *(const float4*)(sp + 8);
    *(float4*)&T[r][c4 + 12] = *(const float4*)(sp + 12);
  }
  __syncthreads();
  {
    const int c  = t >> 2;
    const int rr = (t & 3) * 16;
    unsigned short o[16];
#pragma unroll
    for (int i = 0; i < 16; ++i) o[i] = f2b(T[rr + i][c]);
    unsigned short* dp = dst + (size_t)(c0 + c) * HID + r0 + rr;
    *(bf8v*)dp       = *(bf8v*)&o[0];
    *(bf8v*)(dp + 8) = *(bf8v*)&o[8];
  }
}

// ===========================================================================
// GEMM core v3: 64x128 tile, 8 waves (4M x 2N), BK=64 SUPERSTEPS.
// r22 showed occupancy (28->54%) is NOT the constraint and MfmaUtil stays 18%
// => per-K-step fixed overhead (waitcnt+barrier+issue) dominates (m233).
// Fix: 32 supersteps of K=64 instead of 64 steps of K=32 — half the
// barriers, 8 MFMA/wave between barrier pairs. Same 4x12KB LDS buffers
// (even supersteps use bufs {0,1}, odd {2,3}); next superstep's 2 halves
// are issued FIRST (load-to-use ~1 superstep ≈ 3000cy >> HBM latency).
// T2 both-sides swizzle retained (0 conflicts).
// ===========================================================================

// ---------------------------------------------------------------------------
// QKV GEMM with fused RoPE epilogue + fused V transpose. Grid (24,32)=768,
// 512 threads, 3 blocks/CU exact.
// ---------------------------------------------------------------------------
__global__ __launch_bounds__(512) void gemm_qkv(
    const unsigned short* __restrict__ A, const unsigned short* __restrict__ Bt,
    const float2* __restrict__ tab,
    unsigned short* __restrict__ Qb, unsigned short* __restrict__ Kb,
    unsigned short* __restrict__ Vt) {
  __shared__ unsigned short As[4][64 * 32];
  __shared__ unsigned short Bs[4][128 * 32];
  const int t  = threadIdx.x;
  const int w  = t >> 6, l = t & 63;     // w: 0..7
  const int lr = l & 15, lg = l >> 4;
  const int wr = w >> 1, wc = w & 1;     // wr: 0..3 (M), wc: 0..1 (N)
  const int bm = blockIdx.y * 64, bn = blockIdx.x * 128;

  f4v acc[4] = {};

  const unsigned short* Ablk = A  + (size_t)bm * HID;
  const unsigned short* Bblk = Bt + (size_t)bn * HID;
  const int srow = l >> 2;
  const int scol = (((l & 3) ^ ((srow >> 1) & 3)) * 8);
  const int rsl  = (lg ^ ((lr >> 1) & 3)) * 8;

  // stage both BK=32 halves of superstep u into buffer pair (u&1)*2, +1
  auto stageSS = [&](int u) {
    const int b0 = (u & 1) * 2;
    const int k0 = u * 64;
    if (w < 4) {
      gload16(&As[b0][(w * 16) * 32],     Ablk + (size_t)(w * 16 + srow) * HID + k0 + scol);
      gload16(&As[b0 + 1][(w * 16) * 32], Ablk + (size_t)(w * 16 + srow) * HID + k0 + 32 + scol);
      gload16(&Bs[b0][(w * 16) * 32],     Bblk + (size_t)(w * 16 + srow) * HID + k0 + scol);
      gload16(&Bs[b0 + 1][(w * 16) * 32], Bblk + (size_t)(w * 16 + srow) * HID + k0 + 32 + scol);
    } else {
      gload16(&Bs[b0][(w * 16) * 32],     Bblk + (size_t)(w * 16 + srow) * HID + k0 + scol);
      gload16(&Bs[b0 + 1][(w * 16) * 32], Bblk + (size_t)(w * 16 + srow) * HID + k0 + 32 + scol);
    }
  };

  const int nss = HID / 64;              // 32 supersteps
  stageSS(0);
  asm volatile("s_waitcnt vmcnt(0)" ::: "memory");
  __builtin_amdgcn_s_barrier();

  const int aoff = (wr * 16 + lr) * 32 + rsl;
  const int boff = (wc * 64 + lr) * 32 + rsl;
  for (int u = 0; u < nss; ++u) {
    if (u + 1 < nss) stageSS(u + 1);     // issued first: hides under compute
    const int b0 = (u & 1) * 2;

#pragma unroll
    for (int hlf = 0; hlf < 2; ++hlf) {
      const int cb = b0 + hlf;
      bf8v aF = *(const bf8v*)&As[cb][aoff];
      bf8v bF[4];
#pragma unroll
      for (int j = 0; j < 4; ++j)
        bF[j] = *(const bf8v*)&Bs[cb][boff + j * 512];
      __builtin_amdgcn_s_setprio(1);
#pragma unroll
      for (int ni = 0; ni < 4; ++ni)
        acc[ni] = __builtin_amdgcn_mfma_f32_16x16x32_bf16(aF, bF[ni], acc[ni], 0, 0, 0);
      __builtin_amdgcn_s_setprio(0);
    }

    asm volatile("s_waitcnt vmcnt(0)" ::: "memory");  // u+1 landed (mostly under compute)
    __builtin_amdgcn_s_barrier();
  }

  // Fused epilogue. D layout: row = lg*4+r, col = lr (m89/m91).
  const int row0 = bm + wr * 16;
  const int colHead = bn + wc * 64;
  int mode, hh;                               // 0=Q(rope+scale) 1=K(rope) 2=V(transposed)
  if (colHead < 2048)      { mode = 0; hh = colHead >> 6;          }
  else if (colHead < 2560) { mode = 1; hh = (colHead - 2048) >> 6; }
  else                     { mode = 2; hh = (colHead - 2560) >> 6; }

#pragma unroll
  for (int r = 0; r < 4; ++r) {
    const int rowg = row0 + lg * 4 + r;
    const int bI = rowg >> 10, s = rowg & (SS - 1);
    if (mode == 2) {
      unsigned short* base = Vt + ((size_t)(bI * NKV + hh) * 64) * SS + s;
#pragma unroll
      for (int ni = 0; ni < 4; ++ni)
        base[(size_t)(ni * 16 + lr) * SS] = f2b(acc[ni][r]);
    } else {
      unsigned short* dst = (mode == 0)
          ? Qb + ((size_t)(bI * NH  + hh) * SS + s) * 64
          : Kb + ((size_t)(bI * NKV + hh) * SS + s) * 64;
      const float2 cs_lo = tab[(size_t)rowg * 32 + lr];
      const float2 cs_hi = tab[(size_t)rowg * 32 + 16 + lr];
#pragma unroll
      for (int ni = 0; ni < 4; ++ni) {
        const float2 cs = (ni & 1) ? cs_hi : cs_lo;
        const float x   = acc[ni][r];
        const float prt = acc[ni ^ 2][r];
        const float rh  = (ni < 2) ? -prt : prt;
        float v = x * cs.x + rh * cs.y;
        if (mode == 0) v *= 0.125f;
        dst[ni * 16 + lr] = f2b(v);
      }
    }
  }
}

// ---------------------------------------------------------------------------
// Plain bf16 GEMM for Wo (same v3 core), f32 out. Grid (16,32)=512, 512 thr.
// ---------------------------------------------------------------------------
__global__ __launch_bounds__(512) void gemm_bf16(
    const unsigned short* __restrict__ A, const unsigned short* __restrict__ Bt,
    float* __restrict__ C, int Ndim) {
  __shared__ unsigned short As[4][64 * 32];
  __shared__ unsigned short Bs[4][128 * 32];
  const int t  = threadIdx.x;
  const int w  = t >> 6, l = t & 63;
  const int lr = l & 15, lg = l >> 4;
  const int wr = w >> 1, wc = w & 1;
  const int bm = blockIdx.y * 64, bn = blockIdx.x * 128;

  f4v acc[4] = {};

  const unsigned short* Ablk = A  + (size_t)bm * HID;
  const unsigned short* Bblk = Bt + (size_t)bn * HID;
  const int srow = l >> 2;
  const int scol = (((l & 3) ^ ((srow >> 1) & 3)) * 8);
  const int rsl  = (lg ^ ((lr >> 1) & 3)) * 8;

  auto stageSS = [&](int u) {
    const int b0 = (u & 1) * 2;
    const int k0 = u * 64;
    if (w < 4) {
      gload16(&As[b0][(w * 16) * 32],     Ablk + (size_t)(w * 16 + srow) * HID + k0 + scol);
      gload16(&As[b0 + 1][(w * 16) * 32], Ablk + (size_t)(w * 16 + srow) * HID + k0 + 32 + scol);
      gload16(&Bs[b0][(w * 16) * 32],     Bblk + (size_t)(w * 16 + srow) * HID + k0 + scol);
      gload16(&Bs[b0 + 1][(w * 16) * 32], Bblk + (size_t)(w * 16 + srow) * HID + k0 + 32 + scol);
    } else {
      gload16(&Bs[b0][(w * 16) * 32],     Bblk + (size_t)(w * 16 + srow) * HID + k0 + scol);
      gload16(&Bs[b0 + 1][(w * 16) * 32], Bblk + (size_t)(w * 16 + srow) * HID + k0 + 32 + scol);
    }
  };

  const int nss = HID / 64;
  stageSS(0);
  asm volatile("s_waitcnt vmcnt(0)" ::: "memory");
  __builtin_amdgcn_s_barrier();

  const int aoff = (wr * 16 + lr) * 32 + rsl;
  const int boff = (wc * 64 + lr) * 32 + rsl;
  for (int u = 0; u < nss; ++u) {
    if (u + 1 < nss) stageSS(u + 1);
    const int b0 = (u & 1) * 2;

#pragma unroll
    for (int hlf = 0; hlf < 2; ++hlf) {
      const int cb = b0 + hlf;
      bf8v aF = *(const bf8v*)&As[cb][aoff];
      bf8v bF[4];
#pragma unroll
      for (int j = 0; j < 4; ++j)
        bF[j] = *(const bf8v*)&Bs[cb][boff + j * 512];
      __builtin_amdgcn_s_setprio(1);
#pragma unroll
      for (int ni = 0; ni < 4; ++ni)
        acc[ni] = __builtin_amdgcn_mfma_f32_16x16x32_bf16(aF, bF[ni], acc[ni], 0, 0, 0);
      __builtin_amdgcn_s_setprio(0);
    }

    asm volatile("s_waitcnt vmcnt(0)" ::: "memory");
    __builtin_amdgcn_s_barrier();
  }

  const int row0 = bm + wr * 16;
  const int col0 = bn + wc * 64;
#pragma unroll
  for (int r = 0; r < 4; ++r) {
    const size_t rowoff = (size_t)(row0 + lg * 4 + r) * Ndim;
#pragma unroll
    for (int ni = 0; ni < 4; ++ni)
      C[rowoff + col0 + ni * 16 + lr] = acc[ni][r];
  }
}

// ---------------------------------------------------------------------------
// Flash attention (round-21 best: K-prefetch + T14 V-stage + no-max softmax).
// ---------------------------------------------------------------------------
__global__ __launch_bounds__(128) void attn_mfma(
    const unsigned short* __restrict__ Qb, const unsigned short* __restrict__ Kb,
    const unsigned short* __restrict__ Vt, unsigned short* __restrict__ attn) {
  const int xb = blockIdx.x;
  const int h = blockIdx.y, b = blockIdx.z;
  const int kv = h >> 2;
  const int w  = threadIdx.x >> 6;
  const int l  = threadIdx.x & 63;
  const int lr = l & 15;
  const int lg = l >> 4;
  const int t  = threadIdx.x;

  __shared__ unsigned short VT[64][72];
  __shared__ unsigned short PL[2][16][72];

  const unsigned short* Kp = Kb + ((size_t)((b * NKV + kv) * SS)) * 64;
  const unsigned short* Vp = Vt + ((size_t)((b * NKV + kv) * 64)) * SS;

  const int vd  = t >> 1;
  const int vso = (t & 1) * 32;

  for (int half = 0; half < 2; ++half) {
    const int qt = half ? (31 - xb) : xb;
    const int qbase = qt * 32;
    const int qW = qbase + w * 16;
    const unsigned short* Qp = Qb + ((size_t)((b * NH + h) * SS + qW)) * 64;
    bf8v aQ0 = *(const bf8v*)(Qp + (size_t)lr * 64 + lg * 8);
    bf8v aQ1 = *(const bf8v*)(Qp + (size_t)lr * 64 + 32 + lg * 8);

    f4v o[4] = {{0,0,0,0},{0,0,0,0},{0,0,0,0},{0,0,0,0}};
    float lsumL[4] = {0.f, 0.f, 0.f, 0.f};

    bf8v kc[8];
#pragma unroll
    for (int c = 0; c < 4; ++c) {
      const unsigned short* kr = Kp + (size_t)(c * 16 + lr) * 64 + lg * 8;
      kc[2 * c]     = *(const bf8v*)(kr);
      kc[2 * c + 1] = *(const bf8v*)(kr + 32);
    }

    for (int kvb = 0; kvb < qbase + 32; kvb += 64) {
      __syncthreads();
      const unsigned short* vp = Vp + (size_t)vd * SS + kvb + vso;
      const bf8v v0 = *(const bf8v*)(vp);
      const bf8v v1 = *(const bf8v*)(vp + 8);
      const bf8v v2 = *(const bf8v*)(vp + 16);
      const bf8v v3 = *(const bf8v*)(vp + 24);

      f4v sc[4] = {{0,0,0,0},{0,0,0,0},{0,0,0,0},{0,0,0,0}};
      __builtin_amdgcn_s_setprio(1);
#pragma unroll
      for (int c = 0; c < 4; ++c) {
        sc[c] = __builtin_amdgcn_mfma_f32_16x16x32_bf16(aQ0, kc[2 * c],     sc[c], 0, 0, 0);
        sc[c] = __builtin_amdgcn_mfma_f32_16x16x32_bf16(aQ1, kc[2 * c + 1], sc[c], 0, 0, 0);
      }
      __builtin_amdgcn_s_setprio(0);

      if (kvb + 64 < qbase + 32) {
#pragma unroll
        for (int c = 0; c < 4; ++c) {
          const unsigned short* kr = Kp + (size_t)(kvb + 64 + c * 16 + lr) * 64 + lg * 8;
          kc[2 * c]     = *(const bf8v*)(kr);
          kc[2 * c + 1] = *(const bf8v*)(kr + 32);
        }
      }

#pragma unroll
      for (int r = 0; r < 4; ++r) {
        const int qrow = qW + lg * 4 + r;
        float ps = 0.f;
        unsigned short pb[4];
#pragma unroll
        for (int c = 0; c < 4; ++c) {
          const float s = ((kvb + c * 16 + lr) > qrow) ? -INFINITY : sc[c][r];
          const float p = __expf(s);
          ps += p;
          pb[c] = f2b(p);
        }
        lsumL[r] += ps;
#pragma unroll
        for (int c = 0; c < 4; ++c) PL[w][lg * 4 + r][c * 16 + lr] = pb[c];
      }

      *(bf8v*)&VT[vd][vso]      = v0;
      *(bf8v*)&VT[vd][vso + 8]  = v1;
      *(bf8v*)&VT[vd][vso + 16] = v2;
      *(bf8v*)&VT[vd][vso + 24] = v3;

      __syncthreads();

      bf8v aP0 = *(const bf8v*)&PL[w][lr][lg * 8];
      bf8v aP1 = *(const bf8v*)&PL[w][lr][32 + lg * 8];
      __builtin_amdgcn_s_setprio(1);
#pragma unroll
      for (int n = 0; n < 4; ++n) {
        bf8v bV0 = *(const bf8v*)&VT[n * 16 + lr][lg * 8];
        bf8v bV1 = *(const bf8v*)&VT[n * 16 + lr][32 + lg * 8];
        o[n] = __builtin_amdgcn_mfma_f32_16x16x32_bf16(aP0, bV0, o[n], 0, 0, 0);
        o[n] = __builtin_amdgcn_mfma_f32_16x16x32_bf16(aP1, bV1, o[n], 0, 0, 0);
      }
      __builtin_amdgcn_s_setprio(0);
    }

#pragma unroll
    for (int r = 0; r < 4; ++r) {
      float ls = lsumL[r];
      ls += __shfl_xor(ls, 1);
      ls += __shfl_xor(ls, 2);
      ls += __shfl_xor(ls, 4);
      ls += __shfl_xor(ls, 8);
      const float inv = 1.0f / ls;
      const int row = qW + lg * 4 + r;
      unsigned short* dst = attn + (size_t)(b * SS + row) * HID + h * 64;
#pragma unroll
      for (int n = 0; n < 4; ++n) dst[n * 16 + lr] = f2b(o[n][r] * inv);
    }
  }
}

// ---------------------------------------------------------------------------
extern "C" void kernel_launch(void* const* d_in, const int* in_sizes, int n_in,
                              void* d_out, int out_size, void* d_ws, size_t ws_size,
                              hipStream_t stream) {
  const float* hidden = (const float*)d_in[0];
  const int*   pos    = (const int*)d_in[1];
  const float* Wq = (const float*)d_in[3];
  const float* Wk = (const float*)d_in[4];
  const float* Wv = (const float*)d_in[5];
  const float* Wo = (const float*)d_in[6];
  float* out = (float*)d_out;

  char* ws = (char*)d_ws;
  unsigned short* WqkvT = (unsigned short*)(ws);              // 12 MB  [3072][2048]
  unsigned short* WoT   = (unsigned short*)(ws + 12582912);   //  8 MB  [2048][2048]
  unsigned short* Xb    = (unsigned short*)(ws + 20971520);   //  8 MB  [M][2048]
  unsigned short* attnb = Xb;                                 // alias (Xb dead after gemm_qkv)
  unsigned short* Qb    = (unsigned short*)(ws + 29360128);   //  8 MB  [B][NH][S][64]
  unsigned short* Kb    = (unsigned short*)(ws + 37748736);   //  2 MB  [B][NKV][S][64]
  unsigned short* Vt    = (unsigned short*)(ws + 39845888);   //  2 MB  [B*NKV][64][S]
  float2*         tab   = (float2*)(ws + 41943040);           // 512 KB [M][32]

  dim3 blk(256);

  prepAll<<<dim3(32, 32, 6), blk, 0, stream>>>(Wq, Wk, Wv, Wo, hidden, pos,
                                               WqkvT, WoT, Xb, tab);

  // QKV: 768 blocks x 512 threads = 3 blocks/CU exact, 32 supersteps
  gemm_qkv<<<dim3(NQKV / 128, M / 64), dim3(512), 0, stream>>>(Xb, WqkvT, tab, Qb, Kb, Vt);

  attn_mfma<<<dim3(16, NH, BB), dim3(128), 0, stream>>>(Qb, Kb, Vt, attnb);

  // Wo: 512 blocks x 512 threads = 2 blocks/CU exact, 32 supersteps
  gemm_bf16<<<dim3(HID / 128, M / 64), dim3(512), 0, stream>>>(attnb, WoT, out, HID);
}

// Round 24
// 131.072 us; speedup vs baseline: 1.3301x; 1.0070x over previous
//
#include <hip/hip_runtime.h>
#include <hip/hip_bf16.h>
#include <math.h>

// Problem constants
constexpr int BB   = 2;
constexpr int SS   = 1024;
constexpr int HID  = 2048;
constexpr int NH   = 32;
constexpr int NKV  = 8;
constexpr int HD   = 64;
constexpr int M    = BB * SS;          // 2048 rows
constexpr int NQKV = 3072;             // fused q|k|v output width

typedef __attribute__((ext_vector_type(8))) short bf8v;   // 8 bf16
typedef __attribute__((ext_vector_type(4))) float f4v;    // 4 f32 acc

static __device__ __forceinline__ unsigned short f2b(float x) {
  __hip_bfloat16 h = __float2bfloat16(x);
  return *reinterpret_cast<unsigned short*>(&h);
}
static __device__ __forceinline__ void gload16(void* lds, const void* g) {
  __builtin_amdgcn_global_load_lds(
      (const __attribute__((address_space(1))) void*)g,
      (__attribute__((address_space(3))) void*)lds, 16, 0, 0);
}

// ---------------------------------------------------------------------------
// Fused prep (one launch, grid 32x32x6): weight transposes, RoPE table, castX
// ---------------------------------------------------------------------------
__global__ __launch_bounds__(256) void prepAll(
    const float* __restrict__ Wq, const float* __restrict__ Wk,
    const float* __restrict__ Wv, const float* __restrict__ Wo,
    const float* __restrict__ hidden, const int* __restrict__ pos_ids,
    unsigned short* __restrict__ WqkvT, unsigned short* __restrict__ WoT,
    unsigned short* __restrict__ Xb, float2* __restrict__ tab) {
  const int z = blockIdx.z;
  const int t = threadIdx.x;

  if (z == 4) {            // RoPE table
    const int idx = blockIdx.y * 32 + blockIdx.x;
    if ((t & 127) < 32) {
      const int m = idx * 2 + (t >> 7);
      const int j = t & 31;
      const float pos = (float)pos_ids[m];
      const float ang = pos * exp2f(-(float)j * (13.287712379549449f / 32.0f));
      float sn, cs;
      sincosf(ang, &sn, &cs);
      tab[(size_t)m * 32 + j] = make_float2(cs, sn);
    }
    return;
  }
  if (z == 5) {            // castX
    const size_t base = ((size_t)(blockIdx.y * 32 + blockIdx.x)) * 4096;
#pragma unroll
    for (int it = 0; it < 2; ++it) {
      const size_t i = base + it * 2048 + t * 8;
      const float4 v0 = *(const float4*)(hidden + i);
      const float4 v1 = *(const float4*)(hidden + i + 4);
      unsigned short o[8] = {f2b(v0.x), f2b(v0.y), f2b(v0.z), f2b(v0.w),
                             f2b(v1.x), f2b(v1.y), f2b(v1.z), f2b(v1.w)};
      *(bf8v*)(Xb + i) = *(bf8v*)o;
    }
    return;
  }

  const float* src;
  unsigned short* dst;
  int C;
  if (z == 0)      { src = Wq; dst = WqkvT;                      C = 2048; }
  else if (z == 1) { src = Wk; dst = WqkvT + (size_t)2048 * HID; C = 512;  }
  else if (z == 2) { src = Wv; dst = WqkvT + (size_t)2560 * HID; C = 512;  }
  else             { src = Wo; dst = WoT;                        C = 2048; }

  const int r0 = blockIdx.y * 64, c0 = blockIdx.x * 64;
  if (c0 >= C) return;
  __shared__ float T[64][65];
  {
    const int r  = t >> 2;
    const int c4 = (t & 3) * 16;
    const float* sp = src + (size_t)(r0 + r) * C + c0 + c4;
    *(float4*)&T[r][c4 + 0]  = *(const float4*)(sp + 0);
    *(float4*)&T[r][c4 + 4]  = *(const float4*)(sp + 4);
    *(float4*)&T[r][c4 + 8]  = *(const float4*)(sp + 8);
    *(float4*)&T[r][c4 + 12] = *(const float4*)(sp + 12);
  }
  __syncthreads();
  {
    const int c  = t >> 2;
    const int rr = (t & 3) * 16;
    unsigned short o[16];
#pragma unroll
    for (int i = 0; i < 16; ++i) o[i] = f2b(T[rr + i][c]);
    unsigned short* dp = dst + (size_t)(c0 + c) * HID + r0 + rr;
    *(bf8v*)dp       = *(bf8v*)&o[0];
    *(bf8v*)(dp + 8) = *(bf8v*)&o[8];
  }
}

// ===========================================================================
// GEMM core v3 (round-23 proven): 64x128 tile, 8 waves (4M x 2N), BK=64
// supersteps — half the barriers, 8 MFMA/wave per barrier pair, next
// superstep staged first (load-to-use ~1 superstep). T2 swizzle retained.
// ===========================================================================

// ---------------------------------------------------------------------------
// QKV GEMM with fused RoPE epilogue + fused V transpose. Grid (24,32)=768.
// ---------------------------------------------------------------------------
__global__ __launch_bounds__(512) void gemm_qkv(
    const unsigned short* __restrict__ A, const unsigned short* __restrict__ Bt,
    const float2* __restrict__ tab,
    unsigned short* __restrict__ Qb, unsigned short* __restrict__ Kb,
    unsigned short* __restrict__ Vt) {
  __shared__ unsigned short As[4][64 * 32];
  __shared__ unsigned short Bs[4][128 * 32];
  const int t  = threadIdx.x;
  const int w  = t >> 6, l = t & 63;     // w: 0..7
  const int lr = l & 15, lg = l >> 4;
  const int wr = w >> 1, wc = w & 1;     // wr: 0..3 (M), wc: 0..1 (N)
  const int bm = blockIdx.y * 64, bn = blockIdx.x * 128;

  f4v acc[4] = {};

  const unsigned short* Ablk = A  + (size_t)bm * HID;
  const unsigned short* Bblk = Bt + (size_t)bn * HID;
  const int srow = l >> 2;
  const int scol = (((l & 3) ^ ((srow >> 1) & 3)) * 8);
  const int rsl  = (lg ^ ((lr >> 1) & 3)) * 8;

  auto stageSS = [&](int u) {
    const int b0 = (u & 1) * 2;
    const int k0 = u * 64;
    if (w < 4) {
      gload16(&As[b0][(w * 16) * 32],     Ablk + (size_t)(w * 16 + srow) * HID + k0 + scol);
      gload16(&As[b0 + 1][(w * 16) * 32], Ablk + (size_t)(w * 16 + srow) * HID + k0 + 32 + scol);
      gload16(&Bs[b0][(w * 16) * 32],     Bblk + (size_t)(w * 16 + srow) * HID + k0 + scol);
      gload16(&Bs[b0 + 1][(w * 16) * 32], Bblk + (size_t)(w * 16 + srow) * HID + k0 + 32 + scol);
    } else {
      gload16(&Bs[b0][(w * 16) * 32],     Bblk + (size_t)(w * 16 + srow) * HID + k0 + scol);
      gload16(&Bs[b0 + 1][(w * 16) * 32], Bblk + (size_t)(w * 16 + srow) * HID + k0 + 32 + scol);
    }
  };

  const int nss = HID / 64;              // 32 supersteps
  stageSS(0);
  asm volatile("s_waitcnt vmcnt(0)" ::: "memory");
  __builtin_amdgcn_s_barrier();

  const int aoff = (wr * 16 + lr) * 32 + rsl;
  const int boff = (wc * 64 + lr) * 32 + rsl;
  for (int u = 0; u < nss; ++u) {
    if (u + 1 < nss) stageSS(u + 1);
    const int b0 = (u & 1) * 2;

#pragma unroll
    for (int hlf = 0; hlf < 2; ++hlf) {
      const int cb = b0 + hlf;
      bf8v aF = *(const bf8v*)&As[cb][aoff];
      bf8v bF[4];
#pragma unroll
      for (int j = 0; j < 4; ++j)
        bF[j] = *(const bf8v*)&Bs[cb][boff + j * 512];
      __builtin_amdgcn_s_setprio(1);
#pragma unroll
      for (int ni = 0; ni < 4; ++ni)
        acc[ni] = __builtin_amdgcn_mfma_f32_16x16x32_bf16(aF, bF[ni], acc[ni], 0, 0, 0);
      __builtin_amdgcn_s_setprio(0);
    }

    asm volatile("s_waitcnt vmcnt(0)" ::: "memory");
    __builtin_amdgcn_s_barrier();
  }

  // Fused epilogue. D layout: row = lg*4+r, col = lr (m89/m91).
  const int row0 = bm + wr * 16;
  const int colHead = bn + wc * 64;
  int mode, hh;                               // 0=Q(rope+scale) 1=K(rope) 2=V(transposed)
  if (colHead < 2048)      { mode = 0; hh = colHead >> 6;          }
  else if (colHead < 2560) { mode = 1; hh = (colHead - 2048) >> 6; }
  else                     { mode = 2; hh = (colHead - 2560) >> 6; }

#pragma unroll
  for (int r = 0; r < 4; ++r) {
    const int rowg = row0 + lg * 4 + r;
    const int bI = rowg >> 10, s = rowg & (SS - 1);
    if (mode == 2) {
      unsigned short* base = Vt + ((size_t)(bI * NKV + hh) * 64) * SS + s;
#pragma unroll
      for (int ni = 0; ni < 4; ++ni)
        base[(size_t)(ni * 16 + lr) * SS] = f2b(acc[ni][r]);
    } else {
      unsigned short* dst = (mode == 0)
          ? Qb + ((size_t)(bI * NH  + hh) * SS + s) * 64
          : Kb + ((size_t)(bI * NKV + hh) * SS + s) * 64;
      const float2 cs_lo = tab[(size_t)rowg * 32 + lr];
      const float2 cs_hi = tab[(size_t)rowg * 32 + 16 + lr];
#pragma unroll
      for (int ni = 0; ni < 4; ++ni) {
        const float2 cs = (ni & 1) ? cs_hi : cs_lo;
        const float x   = acc[ni][r];
        const float prt = acc[ni ^ 2][r];
        const float rh  = (ni < 2) ? -prt : prt;
        float v = x * cs.x + rh * cs.y;
        if (mode == 0) v *= 0.125f;
        dst[ni * 16 + lr] = f2b(v);
      }
    }
  }
}

// ---------------------------------------------------------------------------
// Plain bf16 GEMM for Wo (same v3 core), f32 out. Grid (16,32)=512, 512 thr.
// ---------------------------------------------------------------------------
__global__ __launch_bounds__(512) void gemm_bf16(
    const unsigned short* __restrict__ A, const unsigned short* __restrict__ Bt,
    float* __restrict__ C, int Ndim) {
  __shared__ unsigned short As[4][64 * 32];
  __shared__ unsigned short Bs[4][128 * 32];
  const int t  = threadIdx.x;
  const int w  = t >> 6, l = t & 63;
  const int lr = l & 15, lg = l >> 4;
  const int wr = w >> 1, wc = w & 1;
  const int bm = blockIdx.y * 64, bn = blockIdx.x * 128;

  f4v acc[4] = {};

  const unsigned short* Ablk = A  + (size_t)bm * HID;
  const unsigned short* Bblk = Bt + (size_t)bn * HID;
  const int srow = l >> 2;
  const int scol = (((l & 3) ^ ((srow >> 1) & 3)) * 8);
  const int rsl  = (lg ^ ((lr >> 1) & 3)) * 8;

  auto stageSS = [&](int u) {
    const int b0 = (u & 1) * 2;
    const int k0 = u * 64;
    if (w < 4) {
      gload16(&As[b0][(w * 16) * 32],     Ablk + (size_t)(w * 16 + srow) * HID + k0 + scol);
      gload16(&As[b0 + 1][(w * 16) * 32], Ablk + (size_t)(w * 16 + srow) * HID + k0 + 32 + scol);
      gload16(&Bs[b0][(w * 16) * 32],     Bblk + (size_t)(w * 16 + srow) * HID + k0 + scol);
      gload16(&Bs[b0 + 1][(w * 16) * 32], Bblk + (size_t)(w * 16 + srow) * HID + k0 + 32 + scol);
    } else {
      gload16(&Bs[b0][(w * 16) * 32],     Bblk + (size_t)(w * 16 + srow) * HID + k0 + scol);
      gload16(&Bs[b0 + 1][(w * 16) * 32], Bblk + (size_t)(w * 16 + srow) * HID + k0 + 32 + scol);
    }
  };

  const int nss = HID / 64;
  stageSS(0);
  asm volatile("s_waitcnt vmcnt(0)" ::: "memory");
  __builtin_amdgcn_s_barrier();

  const int aoff = (wr * 16 + lr) * 32 + rsl;
  const int boff = (wc * 64 + lr) * 32 + rsl;
  for (int u = 0; u < nss; ++u) {
    if (u + 1 < nss) stageSS(u + 1);
    const int b0 = (u & 1) * 2;

#pragma unroll
    for (int hlf = 0; hlf < 2; ++hlf) {
      const int cb = b0 + hlf;
      bf8v aF = *(const bf8v*)&As[cb][aoff];
      bf8v bF[4];
#pragma unroll
      for (int j = 0; j < 4; ++j)
        bF[j] = *(const bf8v*)&Bs[cb][boff + j * 512];
      __builtin_amdgcn_s_setprio(1);
#pragma unroll
      for (int ni = 0; ni < 4; ++ni)
        acc[ni] = __builtin_amdgcn_mfma_f32_16x16x32_bf16(aF, bF[ni], acc[ni], 0, 0, 0);
      __builtin_amdgcn_s_setprio(0);
    }

    asm volatile("s_waitcnt vmcnt(0)" ::: "memory");
    __builtin_amdgcn_s_barrier();
  }

  const int row0 = bm + wr * 16;
  const int col0 = bn + wc * 64;
#pragma unroll
  for (int r = 0; r < 4; ++r) {
    const size_t rowoff = (size_t)(row0 + lg * 4 + r) * Ndim;
#pragma unroll
    for (int ni = 0; ni < 4; ++ni)
      C[rowoff + col0 + ni * 16 + lr] = acc[ni][r];
  }
}

// ---------------------------------------------------------------------------
// Flash attention v2: DUAL-TILE SUPERSTEPS (the r23 GEMM lever transplanted).
// Per barrier pair process TWO 64-key tiles: stage V(j),V(j+1) to regs ->
// QK^T(j) from kA (then kA <- K(j+2)) -> softmax(j)->PL[0] -> QK^T(j+1)
// from kB (then kB <- K(j+3)) -> softmax(j+1)->PL[1] -> write V tiles ->
// barrier -> PV(j)+PV(j+1). Barriers/block: 34 -> ~20. Two K register sets
// keep K load-to-use >= 1 tile of compute. No-max softmax (scores bounded).
// 2-wave blocks, paired {xb, 31-xb}, grid 16x32x2.
// ---------------------------------------------------------------------------
__global__ __launch_bounds__(128) void attn_mfma(
    const unsigned short* __restrict__ Qb, const unsigned short* __restrict__ Kb,
    const unsigned short* __restrict__ Vt, unsigned short* __restrict__ attn) {
  const int xb = blockIdx.x;
  const int h = blockIdx.y, b = blockIdx.z;
  const int kv = h >> 2;
  const int w  = threadIdx.x >> 6;
  const int l  = threadIdx.x & 63;
  const int lr = l & 15;
  const int lg = l >> 4;
  const int t  = threadIdx.x;

  __shared__ unsigned short VT[2][64][72];      // two V^T tiles
  __shared__ unsigned short PL[2][2][16][72];   // [tile][wave] P

  const unsigned short* Kp = Kb + ((size_t)((b * NKV + kv) * SS)) * 64;
  const unsigned short* Vp = Vt + ((size_t)((b * NKV + kv) * 64)) * SS;

  const int vd  = t >> 1;
  const int vso = (t & 1) * 32;

  for (int half = 0; half < 2; ++half) {
    const int qt = half ? (31 - xb) : xb;
    const int qbase = qt * 32;
    const int qW = qbase + w * 16;
    const unsigned short* Qp = Qb + ((size_t)((b * NH + h) * SS + qW)) * 64;
    bf8v aQ0 = *(const bf8v*)(Qp + (size_t)lr * 64 + lg * 8);
    bf8v aQ1 = *(const bf8v*)(Qp + (size_t)lr * 64 + 32 + lg * 8);

    f4v o[4] = {{0,0,0,0},{0,0,0,0},{0,0,0,0},{0,0,0,0}};
    float lsumL[4] = {0.f, 0.f, 0.f, 0.f};

    const int nkv = (qbase + 32 + 63) >> 6;   // 64-key tiles (block-uniform)

    // K prologue: kA <- tile 0, kB <- tile 1 (if present)
    bf8v kA[8], kB[8];
#pragma unroll
    for (int c = 0; c < 4; ++c) {
      const unsigned short* kr = Kp + (size_t)(c * 16 + lr) * 64 + lg * 8;
      kA[2 * c]     = *(const bf8v*)(kr);
      kA[2 * c + 1] = *(const bf8v*)(kr + 32);
    }
    if (nkv > 1) {
#pragma unroll
      for (int c = 0; c < 4; ++c) {
        const unsigned short* kr = Kp + (size_t)(64 + c * 16 + lr) * 64 + lg * 8;
        kB[2 * c]     = *(const bf8v*)(kr);
        kB[2 * c + 1] = *(const bf8v*)(kr + 32);
      }
    }

    for (int j = 0; j < nkv; j += 2) {
      const bool dual = (j + 1 < nkv);
      __syncthreads();        // prior superstep's VT reads complete

      // (1) V reg-stage for both tiles (T14)
      const unsigned short* vpA = Vp + (size_t)vd * SS + j * 64 + vso;
      const bf8v vA0 = *(const bf8v*)(vpA);
      const bf8v vA1 = *(const bf8v*)(vpA + 8);
      const bf8v vA2 = *(const bf8v*)(vpA + 16);
      const bf8v vA3 = *(const bf8v*)(vpA + 24);
      bf8v vB0, vB1, vB2, vB3;
      if (dual) {
        const unsigned short* vpB = vpA + 64;
        vB0 = *(const bf8v*)(vpB);
        vB1 = *(const bf8v*)(vpB + 8);
        vB2 = *(const bf8v*)(vpB + 16);
        vB3 = *(const bf8v*)(vpB + 24);
      }

      // (2) QK^T tile j from kA
      {
        f4v sc[4] = {{0,0,0,0},{0,0,0,0},{0,0,0,0},{0,0,0,0}};
        __builtin_amdgcn_s_setprio(1);
#pragma unroll
        for (int c = 0; c < 4; ++c) {
          sc[c] = __builtin_amdgcn_mfma_f32_16x16x32_bf16(aQ0, kA[2 * c],     sc[c], 0, 0, 0);
          sc[c] = __builtin_amdgcn_mfma_f32_16x16x32_bf16(aQ1, kA[2 * c + 1], sc[c], 0, 0, 0);
        }
        __builtin_amdgcn_s_setprio(0);
        // kA <- tile j+2 (lands during softmax+PV)
        if (j + 2 < nkv) {
#pragma unroll
          for (int c = 0; c < 4; ++c) {
            const unsigned short* kr = Kp + (size_t)((j + 2) * 64 + c * 16 + lr) * 64 + lg * 8;
            kA[2 * c]     = *(const bf8v*)(kr);
            kA[2 * c + 1] = *(const bf8v*)(kr + 32);
          }
        }
        // softmax tile j -> PL[0][w]
#pragma unroll
        for (int r = 0; r < 4; ++r) {
          const int qrow = qW + lg * 4 + r;
          float ps = 0.f;
          unsigned short pb[4];
#pragma unroll
          for (int c = 0; c < 4; ++c) {
            const float s = ((j * 64 + c * 16 + lr) > qrow) ? -INFINITY : sc[c][r];
            const float p = __expf(s);
            ps += p;
            pb[c] = f2b(p);
          }
          lsumL[r] += ps;
#pragma unroll
          for (int c = 0; c < 4; ++c) PL[0][w][lg * 4 + r][c * 16 + lr] = pb[c];
        }
      }

      // (3) QK^T tile j+1 from kB
      if (dual) {
        f4v sc[4] = {{0,0,0,0},{0,0,0,0},{0,0,0,0},{0,0,0,0}};
        __builtin_amdgcn_s_setprio(1);
#pragma unroll
        for (int c = 0; c < 4; ++c) {
          sc[c] = __builtin_amdgcn_mfma_f32_16x16x32_bf16(aQ0, kB[2 * c],     sc[c], 0, 0, 0);
          sc[c] = __builtin_amdgcn_mfma_f32_16x16x32_bf16(aQ1, kB[2 * c + 1], sc[c], 0, 0, 0);
        }
        __builtin_amdgcn_s_setprio(0);
        // kB <- tile j+3
        if (j + 3 < nkv) {
#pragma unroll
          for (int c = 0; c < 4; ++c) {
            const unsigned short* kr = Kp + (size_t)((j + 3) * 64 + c * 16 + lr) * 64 + lg * 8;
            kB[2 * c]     = *(const bf8v*)(kr);
            kB[2 * c + 1] = *(const bf8v*)(kr + 32);
          }
        }
        // softmax tile j+1 -> PL[1][w]
#pragma unroll
        for (int r = 0; r < 4; ++r) {
          const int qrow = qW + lg * 4 + r;
          float ps = 0.f;
          unsigned short pb[4];
#pragma unroll
          for (int c = 0; c < 4; ++c) {
            const float s = (((j + 1) * 64 + c * 16 + lr) > qrow) ? -INFINITY : sc[c][r];
            const float p = __expf(s);
            ps += p;
            pb[c] = f2b(p);
          }
          lsumL[r] += ps;
#pragma unroll
          for (int c = 0; c < 4; ++c) PL[1][w][lg * 4 + r][c * 16 + lr] = pb[c];
        }
      }

      // (4) staged V -> LDS (vmcnt waits hidden under QK^T + softmax)
      *(bf8v*)&VT[0][vd][vso]      = vA0;
      *(bf8v*)&VT[0][vd][vso + 8]  = vA1;
      *(bf8v*)&VT[0][vd][vso + 16] = vA2;
      *(bf8v*)&VT[0][vd][vso + 24] = vA3;
      if (dual) {
        *(bf8v*)&VT[1][vd][vso]      = vB0;
        *(bf8v*)&VT[1][vd][vso + 8]  = vB1;
        *(bf8v*)&VT[1][vd][vso + 16] = vB2;
        *(bf8v*)&VT[1][vd][vso + 24] = vB3;
      }

      __syncthreads();        // VT visible (PL is own-wave)

      // (5) PV for both tiles
      {
        bf8v aP0 = *(const bf8v*)&PL[0][w][lr][lg * 8];
        bf8v aP1 = *(const bf8v*)&PL[0][w][lr][32 + lg * 8];
        __builtin_amdgcn_s_setprio(1);
#pragma unroll
        for (int n = 0; n < 4; ++n) {
          bf8v bV0 = *(const bf8v*)&VT[0][n * 16 + lr][lg * 8];
          bf8v bV1 = *(const bf8v*)&VT[0][n * 16 + lr][32 + lg * 8];
          o[n] = __builtin_amdgcn_mfma_f32_16x16x32_bf16(aP0, bV0, o[n], 0, 0, 0);
          o[n] = __builtin_amdgcn_mfma_f32_16x16x32_bf16(aP1, bV1, o[n], 0, 0, 0);
        }
        __builtin_amdgcn_s_setprio(0);
      }
      if (dual) {
        bf8v aP0 = *(const bf8v*)&PL[1][w][lr][lg * 8];
        bf8v aP1 = *(const bf8v*)&PL[1][w][lr][32 + lg * 8];
        __builtin_amdgcn_s_setprio(1);
#pragma unroll
        for (int n = 0; n < 4; ++n) {
          bf8v bV0 = *(const bf8v*)&VT[1][n * 16 + lr][lg * 8];
          bf8v bV1 = *(const bf8v*)&VT[1][n * 16 + lr][32 + lg * 8];
          o[n] = __builtin_amdgcn_mfma_f32_16x16x32_bf16(aP0, bV0, o[n], 0, 0, 0);
          o[n] = __builtin_amdgcn_mfma_f32_16x16x32_bf16(aP1, bV1, o[n], 0, 0, 0);
        }
        __builtin_amdgcn_s_setprio(0);
      }
    }

    // epilogue: reduce per-lane lsum, divide, store
#pragma unroll
    for (int r = 0; r < 4; ++r) {
      float ls = lsumL[r];
      ls += __shfl_xor(ls, 1);
      ls += __shfl_xor(ls, 2);
      ls += __shfl_xor(ls, 4);
      ls += __shfl_xor(ls, 8);
      const float inv = 1.0f / ls;
      const int row = qW + lg * 4 + r;
      unsigned short* dst = attn + (size_t)(b * SS + row) * HID + h * 64;
#pragma unroll
      for (int n = 0; n < 4; ++n) dst[n * 16 + lr] = f2b(o[n][r] * inv);
    }
  }
}

// ---------------------------------------------------------------------------
extern "C" void kernel_launch(void* const* d_in, const int* in_sizes, int n_in,
                              void* d_out, int out_size, void* d_ws, size_t ws_size,
                              hipStream_t stream) {
  const float* hidden = (const float*)d_in[0];
  const int*   pos    = (const int*)d_in[1];
  const float* Wq = (const float*)d_in[3];
  const float* Wk = (const float*)d_in[4];
  const float* Wv = (const float*)d_in[5];
  const float* Wo = (const float*)d_in[6];
  float* out = (float*)d_out;

  char* ws = (char*)d_ws;
  unsigned short* WqkvT = (unsigned short*)(ws);              // 12 MB  [3072][2048]
  unsigned short* WoT   = (unsigned short*)(ws + 12582912);   //  8 MB  [2048][2048]
  unsigned short* Xb    = (unsigned short*)(ws + 20971520);   //  8 MB  [M][2048]
  unsigned short* attnb = Xb;                                 // alias (Xb dead after gemm_qkv)
  unsigned short* Qb    = (unsigned short*)(ws + 29360128);   //  8 MB  [B][NH][S][64]
  unsigned short* Kb    = (unsigned short*)(ws + 37748736);   //  2 MB  [B][NKV][S][64]
  unsigned short* Vt    = (unsigned short*)(ws + 39845888);   //  2 MB  [B*NKV][64][S]
  float2*         tab   = (float2*)(ws + 41943040);           // 512 KB [M][32]

  dim3 blk(256);

  prepAll<<<dim3(32, 32, 6), blk, 0, stream>>>(Wq, Wk, Wv, Wo, hidden, pos,
                                               WqkvT, WoT, Xb, tab);

  // QKV: 768 blocks x 512 threads = 3 blocks/CU exact, 32 supersteps
  gemm_qkv<<<dim3(NQKV / 128, M / 64), dim3(512), 0, stream>>>(Xb, WqkvT, tab, Qb, Kb, Vt);

  attn_mfma<<<dim3(16, NH, BB), dim3(128), 0, stream>>>(Qb, Kb, Vt, attnb);

  // Wo: 512 blocks x 512 threads = 2 blocks/CU exact, 32 supersteps
  gemm_bf16<<<dim3(HID / 128, M / 64), dim3(512), 0, stream>>>(attnb, WoT, out, HID);
}